// Round 18
// baseline (735.938 us; speedup 1.0000x reference)
//
#include <hip/hip_runtime.h>
#include <hip/hip_bf16.h>

typedef __hip_bfloat16 bf;
typedef __attribute__((ext_vector_type(4))) float f32x4;
typedef __attribute__((ext_vector_type(8))) __bf16 bf16x8;
typedef __attribute__((ext_vector_type(8))) short short8;
typedef __attribute__((ext_vector_type(4))) short short4v;

#define NN 12000
#define DD 128
#define HIDC 256
#define BBATCH 512
#define LSEQ 20
#define FFEAT 400
#define FFDIM 512
#define AZ 5
#define AKS (NN / AZ)     // 2400 = 37*64 + 32

__device__ __forceinline__ float b2f(bf v) { return __bfloat162float(v); }
__device__ __forceinline__ bf f2b(float v) { return __float2bfloat16(v); }
__device__ __forceinline__ float us2f(unsigned short u) {
    return __uint_as_float(((unsigned int)u) << 16);
}
__device__ __forceinline__ unsigned short f2us(float f) {
    bf h = __float2bfloat16(f);
    return __builtin_bit_cast(unsigned short, h);
}

__device__ __forceinline__ void gload_lds16(const bf* g, bf* l) {
    __builtin_amdgcn_global_load_lds(
        (__attribute__((address_space(1))) void*)(g),
        (__attribute__((address_space(3))) void*)(l),
        16, 0, 0);
}

template<bool F32>
__device__ __forceinline__ short8 ld8(const void* p, long long idx) {
    if (F32) {
        const float* fp = (const float*)p + idx;
        f32x4 u0 = *(const f32x4*)fp;
        f32x4 u1 = *(const f32x4*)(fp + 4);
        short8 s;
        s[0] = (short)f2us(u0[0]); s[1] = (short)f2us(u0[1]);
        s[2] = (short)f2us(u0[2]); s[3] = (short)f2us(u0[3]);
        s[4] = (short)f2us(u1[0]); s[5] = (short)f2us(u1[1]);
        s[6] = (short)f2us(u1[2]); s[7] = (short)f2us(u1[3]);
        return s;
    } else {
        return *(const short8*)((const bf*)p + idx);
    }
}

template<bool F32>
__device__ __forceinline__ bf ldelem(const void* p, long long idx) {
    if (F32) return f2b(((const float*)p)[idx]);
    return ((const bf*)p)[idx];
}

// ---------------------------------------------------------------------------
// adj pass v8 (R13 best): BK=64, 4-buffer ring, prefetch 3, one barrier/step.
// ---------------------------------------------------------------------------
__global__ __launch_bounds__(512) void adj_gemm8(
    const bf* __restrict__ A,    // adjb [NN][NN]
    const bf* __restrict__ Bt,   // BT [128][NN]
    float* __restrict__ part)    // [AZ][NN][128]
{
    alignas(16) __shared__ bf As[4][128 * 64];
    alignas(16) __shared__ bf Bs[4][128 * 64];
    const int tid = threadIdx.x;
    const int lane = tid & 63;
    const int w = tid >> 6;                       // 0..7
    const int z = blockIdx.y;
    const long long k0 = (long long)z * AKS;
    int m0 = blockIdx.x * 128;
    if (m0 > NN - 128) m0 = NN - 128;

    const int rowi = lane >> 3;
    const int chks = (lane & 7) ^ rowi;
    const bf* gA[2]; const bf* gB[2]; int lo[2];
    #pragma unroll
    for (int i = 0; i < 2; i++) {
        int rbase = 16 * w + 8 * i;
        gA[i] = A  + (long long)(m0 + rbase + rowi) * NN + k0 + chks * 8;
        gB[i] = Bt + (long long)(rbase + rowi) * NN + k0 + chks * 8;
        lo[i] = rbase * 64;
    }
    const int rowiT = lane >> 2;
    const int chksT = (lane & 3) ^ ((lane >> 3) & 3);
    const bf* gAT = A  + (long long)(m0 + 16 * w + rowiT) * NN + k0 + 2368 + chksT * 8;
    const bf* gBT = Bt + (long long)(16 * w + rowiT) * NN + k0 + 2368 + chksT * 8;
    const int loT = (16 * w) * 32;

    const int wr = (w >> 1) * 32, wc = (w & 1) * 64;
    const int fr = lane & 15;
    const int kq = lane >> 4;
    int aoff[2][2], boff[2][4], aoffT[2], boffT[4];
    #pragma unroll
    for (int mi = 0; mi < 2; mi++) {
        int ra = wr + mi * 16 + fr;
        aoff[0][mi] = ra * 64 + ((kq)     ^ (ra & 7)) * 8;
        aoff[1][mi] = ra * 64 + ((4 + kq) ^ (ra & 7)) * 8;
        aoffT[mi]   = ra * 32 + (kq ^ ((ra >> 1) & 3)) * 8;
    }
    #pragma unroll
    for (int ni = 0; ni < 4; ni++) {
        int rb = wc + ni * 16 + fr;
        boff[0][ni] = rb * 64 + ((kq)     ^ (rb & 7)) * 8;
        boff[1][ni] = rb * 64 + ((4 + kq) ^ (rb & 7)) * 8;
        boffT[ni]   = rb * 32 + (kq ^ ((rb >> 1) & 3)) * 8;
    }
    f32x4 acc[2][4] = {};

    auto stage64 = [&](int t, int b) {
        const long long go = (long long)t * 64;
        const int bo = b * (128 * 64);
        #pragma unroll
        for (int i = 0; i < 2; i++) {
            gload_lds16(gA[i] + go, &As[0][0] + bo + lo[i]);
            gload_lds16(gB[i] + go, &Bs[0][0] + bo + lo[i]);
        }
    };
    auto stageTail = [&]() {
        gload_lds16(gAT, &As[1][0] + loT);
        gload_lds16(gBT, &Bs[1][0] + loT);
    };
    auto compute64 = [&](int b) {
        const bf* Ab = &As[0][0] + b * (128 * 64);
        const bf* Bb = &Bs[0][0] + b * (128 * 64);
        #pragma unroll
        for (int s = 0; s < 2; s++) {
            bf16x8 af[2], bfr[4];
            #pragma unroll
            for (int mi = 0; mi < 2; mi++) af[mi]  = *(const bf16x8*)(Ab + aoff[s][mi]);
            #pragma unroll
            for (int ni = 0; ni < 4; ni++) bfr[ni] = *(const bf16x8*)(Bb + boff[s][ni]);
            #pragma unroll
            for (int mi = 0; mi < 2; mi++)
                #pragma unroll
                for (int ni = 0; ni < 4; ni++)
                    acc[mi][ni] = __builtin_amdgcn_mfma_f32_16x16x32_bf16(
                        af[mi], bfr[ni], acc[mi][ni], 0, 0, 0);
        }
    };

    stage64(0, 0);
    stage64(1, 1);
    stage64(2, 2);

    #pragma unroll 1
    for (int t = 0; t < 35; t++) {
        asm volatile("s_waitcnt vmcnt(8)" ::: "memory");
        __builtin_amdgcn_s_barrier();
        __builtin_amdgcn_sched_barrier(0);
        compute64(t & 3);
        if (t < 34) stage64(t + 3, (t + 3) & 3);
        else        stageTail();
    }
    asm volatile("s_waitcnt vmcnt(6)" ::: "memory");
    __builtin_amdgcn_s_barrier();
    __builtin_amdgcn_sched_barrier(0);
    compute64(3);
    asm volatile("s_waitcnt vmcnt(2)" ::: "memory");
    __builtin_amdgcn_s_barrier();
    __builtin_amdgcn_sched_barrier(0);
    compute64(0);
    asm volatile("s_waitcnt vmcnt(0)" ::: "memory");
    __builtin_amdgcn_s_barrier();
    __builtin_amdgcn_sched_barrier(0);
    {
        bf16x8 af[2], bfr[4];
        #pragma unroll
        for (int mi = 0; mi < 2; mi++) af[mi]  = *(const bf16x8*)(&As[1][0] + aoffT[mi]);
        #pragma unroll
        for (int ni = 0; ni < 4; ni++) bfr[ni] = *(const bf16x8*)(&Bs[1][0] + boffT[ni]);
        #pragma unroll
        for (int mi = 0; mi < 2; mi++)
            #pragma unroll
            for (int ni = 0; ni < 4; ni++)
                acc[mi][ni] = __builtin_amdgcn_mfma_f32_16x16x32_bf16(
                    af[mi], bfr[ni], acc[mi][ni], 0, 0, 0);
    }

    float* C = part + (long long)z * ((long long)NN * 128);
    const int cr0 = (lane >> 4) * 4;
    const int cc = lane & 15;
    #pragma unroll
    for (int mi = 0; mi < 2; mi++) {
        #pragma unroll
        for (int ni = 0; ni < 4; ni++) {
            int col = wc + ni * 16 + cc;
            #pragma unroll
            for (int j = 0; j < 4; j++) {
                int row = m0 + wr + mi * 16 + cr0 + j;
                C[(long long)row * 128 + col] = acc[mi][ni][j];
            }
        }
    }
}

// ---------------------------------------------------------------------------
// Generic batched MFMA GEMM: C = act(alpha * A @ B^T + bias)
// ---------------------------------------------------------------------------
template<bool A_F32, bool B_F32, bool HAS_BIAS, bool RELU, bool OUT_F32, bool SIDE_A>
__global__ __launch_bounds__(256) void gemm128(
    const void* __restrict__ A, int lda, long long sA1, long long sA2,
    const void* __restrict__ Bm, int ldb, long long sB1, long long sB2,
    const float* __restrict__ bias,
    void* __restrict__ Cv, int ldc, long long sC1, long long sC2,
    int M, int N, int K, int tilesN, int zdiv, float alpha,
    bf* __restrict__ sideA)
{
    __shared__ bf As[128][40];
    __shared__ bf Bs[128][40];
    const int tid = threadIdx.x;
    const int z = blockIdx.y;
    const int zq = z / zdiv, zr = z - zq * zdiv;
    const char* Ap = (const char*)A;
    const char* Bp = (const char*)Bm;
    const long long offA = (long long)zq * sA1 + (long long)zr * sA2;
    const long long offB = (long long)zq * sB1 + (long long)zr * sB2;
    const long long offC = (long long)zq * sC1 + (long long)zr * sC2;
    const int tm = blockIdx.x / tilesN, tn = blockIdx.x - tm * tilesN;
    int m0 = tm * 128; if (m0 > M - 128) m0 = M - 128;
    const int n0 = tn * 128;
    const int lane = tid & 63;
    const int wv = tid >> 6;
    const int wr = (wv >> 1) * 64, wc = (wv & 1) * 64;
    const int fr = lane & 15;
    const int kq = (lane >> 4) * 8;
    const int sr = tid >> 2, scol = (tid & 3) * 8;
    f32x4 acc[4][4] = {};

    for (int k0 = 0; k0 < K; k0 += 32) {
        if (k0 + 32 <= K) {
            const long long ia0 = offA + (long long)(m0 + sr) * lda + k0 + scol;
            const long long ia1 = offA + (long long)(m0 + sr + 64) * lda + k0 + scol;
            short8 va0 = ld8<A_F32>(Ap, ia0);
            short8 va1 = ld8<A_F32>(Ap, ia1);
            short8 vb0 = {0,0,0,0,0,0,0,0}, vb1 = {0,0,0,0,0,0,0,0};
            if (n0 + sr < N)      vb0 = ld8<B_F32>(Bp, offB + (long long)(n0 + sr) * ldb + k0 + scol);
            if (n0 + sr + 64 < N) vb1 = ld8<B_F32>(Bp, offB + (long long)(n0 + sr + 64) * ldb + k0 + scol);
            if (SIDE_A) {
                *(short8*)&sideA[ia0] = va0;
                *(short8*)&sideA[ia1] = va1;
            }
            *(short8*)&As[sr][scol] = va0;
            *(short8*)&As[sr + 64][scol] = va1;
            *(short8*)&Bs[sr][scol] = vb0;
            *(short8*)&Bs[sr + 64][scol] = vb1;
        } else {
            bf zv = f2b(0.f);
            for (int i = tid; i < 128 * 32; i += 256) {
                int r = i >> 5, c = i & 31, gk = k0 + c;
                As[r][c] = (gk < K) ? ldelem<A_F32>(Ap, offA + (long long)(m0 + r) * lda + gk) : zv;
                Bs[r][c] = (gk < K && n0 + r < N) ? ldelem<B_F32>(Bp, offB + (long long)(n0 + r) * ldb + gk) : zv;
            }
        }
        __syncthreads();
        bf16x8 af[4], bfg[4];
        #pragma unroll
        for (int i = 0; i < 4; i++) af[i]  = *(const bf16x8*)&As[wr + i * 16 + fr][kq];
        #pragma unroll
        for (int i = 0; i < 4; i++) bfg[i] = *(const bf16x8*)&Bs[wc + i * 16 + fr][kq];
        #pragma unroll
        for (int mi = 0; mi < 4; mi++)
            #pragma unroll
            for (int ni = 0; ni < 4; ni++)
                acc[mi][ni] = __builtin_amdgcn_mfma_f32_16x16x32_bf16(
                    af[mi], bfg[ni], acc[mi][ni], 0, 0, 0);
        __syncthreads();
    }

    const int cr0 = (lane >> 4) * 4;
    const int cc = lane & 15;
    #pragma unroll
    for (int mi = 0; mi < 4; mi++) {
        #pragma unroll
        for (int ni = 0; ni < 4; ni++) {
            int col = n0 + wc + ni * 16 + cc;
            if (col >= N) continue;
            float bv = 0.f;
            if (HAS_BIAS) bv = bias[col];
            #pragma unroll
            for (int j = 0; j < 4; j++) {
                int row = m0 + wr + mi * 16 + cr0 + j;
                float v = acc[mi][ni][j] * alpha + bv;
                if (RELU) v = fmaxf(v, 0.f);
                if (OUT_F32) ((float*)Cv)[offC + (long long)row * ldc + col] = v;
                else ((bf*)Cv)[offC + (long long)row * ldc + col] = f2b(v);
            }
        }
    }
}

// ---------------------------------------------------------------------------
// qkv GEMM with gathered A rows: A row r = item[useqs[r]]. Replaces
// gather_rows + the seq buffer. M=10240, N=384, K=128, tilesN=3.
// ---------------------------------------------------------------------------
__global__ __launch_bounds__(256) void gemm_qkv(
    const bf* __restrict__ item, const int* __restrict__ idx,
    const float* __restrict__ Bw,    // ipw [384][128]
    const float* __restrict__ bias,  // ipb [384]
    bf* __restrict__ qkv)            // [10240][384]
{
    __shared__ bf As[128][40];
    __shared__ bf Bs[128][40];
    const int tid = threadIdx.x;
    const int tm = blockIdx.x / 3, tn = blockIdx.x - tm * 3;
    const int m0 = tm * 128;
    const int n0 = tn * 128;
    const int lane = tid & 63;
    const int wv = tid >> 6;
    const int wr = (wv >> 1) * 64, wc = (wv & 1) * 64;
    const int fr = lane & 15;
    const int kq = (lane >> 4) * 8;
    const int sr = tid >> 2, scol = (tid & 3) * 8;
    const long long ga0 = (long long)idx[m0 + sr] * 128;
    const long long ga1 = (long long)idx[m0 + sr + 64] * 128;
    f32x4 acc[4][4] = {};

    for (int k0 = 0; k0 < 128; k0 += 32) {
        *(short8*)&As[sr][scol]      = *(const short8*)(item + ga0 + k0 + scol);
        *(short8*)&As[sr + 64][scol] = *(const short8*)(item + ga1 + k0 + scol);
        *(short8*)&Bs[sr][scol]      = ld8<true>(Bw, (long long)(n0 + sr) * 128 + k0 + scol);
        *(short8*)&Bs[sr + 64][scol] = ld8<true>(Bw, (long long)(n0 + sr + 64) * 128 + k0 + scol);
        __syncthreads();
        bf16x8 af[4], bfg[4];
        #pragma unroll
        for (int i = 0; i < 4; i++) af[i]  = *(const bf16x8*)&As[wr + i * 16 + fr][kq];
        #pragma unroll
        for (int i = 0; i < 4; i++) bfg[i] = *(const bf16x8*)&Bs[wc + i * 16 + fr][kq];
        #pragma unroll
        for (int mi = 0; mi < 4; mi++)
            #pragma unroll
            for (int ni = 0; ni < 4; ni++)
                acc[mi][ni] = __builtin_amdgcn_mfma_f32_16x16x32_bf16(
                    af[mi], bfg[ni], acc[mi][ni], 0, 0, 0);
        __syncthreads();
    }

    const int cr0 = (lane >> 4) * 4;
    const int cc = lane & 15;
    #pragma unroll
    for (int mi = 0; mi < 4; mi++) {
        #pragma unroll
        for (int ni = 0; ni < 4; ni++) {
            int col = n0 + wc + ni * 16 + cc;
            float bv = bias[col];
            #pragma unroll
            for (int j = 0; j < 4; j++) {
                int row = m0 + wr + mi * 16 + cr0 + j;
                qkv[(long long)row * 384 + col] = f2b(acc[mi][ni][j] + bv);
            }
        }
    }
}

// ---------------------------------------------------------------------------
// t2 GEMM with TRANSPOSED output (R16-verified).
// ---------------------------------------------------------------------------
__global__ __launch_bounds__(256) void gemm_t2(
    const bf* __restrict__ A,
    const bf* __restrict__ Bw,
    bf* __restrict__ BT)
{
    __shared__ bf As[128][40];
    __shared__ bf Bs[128][40];
    const int tid = threadIdx.x;
    int m0 = blockIdx.x * 128;
    if (m0 > NN - 128) m0 = NN - 128;
    const int lane = tid & 63;
    const int wv = tid >> 6;
    const int wr = (wv >> 1) * 64, wc = (wv & 1) * 64;
    const int fr = lane & 15;
    const int kq = (lane >> 4) * 8;
    const int sr = tid >> 2, scol = (tid & 3) * 8;
    f32x4 acc[4][4] = {};

    for (int k0 = 0; k0 < 256; k0 += 32) {
        *(short8*)&As[sr][scol]      = ld8<false>(A, (long long)(m0 + sr) * 256 + k0 + scol);
        *(short8*)&As[sr + 64][scol] = ld8<false>(A, (long long)(m0 + sr + 64) * 256 + k0 + scol);
        *(short8*)&Bs[sr][scol]      = ld8<false>(Bw, (long long)sr * 256 + k0 + scol);
        *(short8*)&Bs[sr + 64][scol] = ld8<false>(Bw, (long long)(sr + 64) * 256 + k0 + scol);
        __syncthreads();
        bf16x8 af[4], bfg[4];
        #pragma unroll
        for (int i = 0; i < 4; i++) af[i]  = *(const bf16x8*)&As[wr + i * 16 + fr][kq];
        #pragma unroll
        for (int i = 0; i < 4; i++) bfg[i] = *(const bf16x8*)&Bs[wc + i * 16 + fr][kq];
        #pragma unroll
        for (int mi = 0; mi < 4; mi++)
            #pragma unroll
            for (int ni = 0; ni < 4; ni++)
                acc[mi][ni] = __builtin_amdgcn_mfma_f32_16x16x32_bf16(
                    af[mi], bfg[ni], acc[mi][ni], 0, 0, 0);
        __syncthreads();
    }

    const int cr0 = (lane >> 4) * 4;
    const int cc = lane & 15;
    #pragma unroll
    for (int mi = 0; mi < 4; mi++) {
        #pragma unroll
        for (int ni = 0; ni < 4; ni++) {
            int col = wc + ni * 16 + cc;
            int rowb = m0 + wr + mi * 16 + cr0;
            short4v v;
            #pragma unroll
            for (int j = 0; j < 4; j++) v[j] = (short)f2us(acc[mi][ni][j]);
            *(short4v*)&BT[(long long)col * NN + rowb] = v;
        }
    }
}

// ---------------------------------------------------------------------------
// 5-way partial reduce + bias with transposed output (R16-verified).
// ---------------------------------------------------------------------------
__global__ __launch_bounds__(256) void reduceKT(
    const float* __restrict__ part, const float* __restrict__ bias,
    bf* __restrict__ BT)
{
    __shared__ bf t[32][33];
    const long long zs = (long long)NN * 128;
    int r0 = blockIdx.x * 32, c0 = blockIdx.y * 32;
    int tx = threadIdx.x, ty = threadIdx.y;   // 32 x 8
    #pragma unroll
    for (int i = 0; i < 4; i++) {
        int r = r0 + ty + i * 8, c = c0 + tx;
        float s = bias[c];
        #pragma unroll
        for (int z = 0; z < AZ; z++) s += part[(long long)z * zs + (long long)r * 128 + c];
        t[ty + i * 8][tx] = f2b(s);
    }
    __syncthreads();
    #pragma unroll
    for (int i = 0; i < 4; i++) {
        int c = c0 + ty + i * 8, r = r0 + tx;
        BT[(long long)c * NN + r] = t[tx][ty + i * 8];
    }
}

// ---------------------------------------------------------------------------
// GEMM with fused residual + LayerNorm epilogue. Residual row may be
// indirected via ridx (resid row = ridx[row]) to read gathered sources.
// ---------------------------------------------------------------------------
__global__ __launch_bounds__(256) void gemm_ln(
    const bf* __restrict__ A, int lda,
    const float* __restrict__ Bw,
    const float* __restrict__ bias,
    const bf* __restrict__ resid,
    const int* __restrict__ ridx,
    const float* __restrict__ lnS, const float* __restrict__ lnB,
    bf* __restrict__ outp, int K)
{
    __shared__ bf As[128][40];
    __shared__ bf Bs[128][40];
    __shared__ float red[128][2][2];
    const int tid = threadIdx.x;
    const int m0 = blockIdx.x * 128;
    const int lane = tid & 63;
    const int wv = tid >> 6;
    const int wr = (wv >> 1) * 64, wc = (wv & 1) * 64;
    const int fr = lane & 15;
    const int kq = (lane >> 4) * 8;
    const int sr = tid >> 2, scol = (tid & 3) * 8;
    f32x4 acc[4][4] = {};

    for (int k0 = 0; k0 < K; k0 += 32) {
        short8 va0 = ld8<false>(A, (long long)(m0 + sr) * lda + k0 + scol);
        short8 va1 = ld8<false>(A, (long long)(m0 + sr + 64) * lda + k0 + scol);
        short8 vb0 = ld8<true>(Bw, (long long)sr * K + k0 + scol);
        short8 vb1 = ld8<true>(Bw, (long long)(sr + 64) * K + k0 + scol);
        *(short8*)&As[sr][scol] = va0;
        *(short8*)&As[sr + 64][scol] = va1;
        *(short8*)&Bs[sr][scol] = vb0;
        *(short8*)&Bs[sr + 64][scol] = vb1;
        __syncthreads();
        bf16x8 af[4], bfg[4];
        #pragma unroll
        for (int i = 0; i < 4; i++) af[i]  = *(const bf16x8*)&As[wr + i * 16 + fr][kq];
        #pragma unroll
        for (int i = 0; i < 4; i++) bfg[i] = *(const bf16x8*)&Bs[wc + i * 16 + fr][kq];
        #pragma unroll
        for (int mi = 0; mi < 4; mi++)
            #pragma unroll
            for (int ni = 0; ni < 4; ni++)
                acc[mi][ni] = __builtin_amdgcn_mfma_f32_16x16x32_bf16(
                    af[mi], bfg[ni], acc[mi][ni], 0, 0, 0);
        __syncthreads();
    }

    const int cr0 = (lane >> 4) * 4;
    const int cc = lane & 15;
    #pragma unroll
    for (int mi = 0; mi < 4; mi++)
        #pragma unroll
        for (int ni = 0; ni < 4; ni++) {
            int col = wc + ni * 16 + cc;
            #pragma unroll
            for (int j = 0; j < 4; j++) {
                int row = m0 + wr + mi * 16 + cr0 + j;
                long long rr = ridx ? (long long)ridx[row] : (long long)row;
                acc[mi][ni][j] += bias[col] + b2f(resid[rr * 128 + col]);
            }
        }
    float s1[4][4], s2[4][4];
    #pragma unroll
    for (int mi = 0; mi < 4; mi++)
        #pragma unroll
        for (int j = 0; j < 4; j++) {
            float a = 0.f, b = 0.f;
            #pragma unroll
            for (int ni = 0; ni < 4; ni++) {
                float x = acc[mi][ni][j];
                a += x; b += x * x;
            }
            #pragma unroll
            for (int off = 1; off < 16; off <<= 1) {
                a += __shfl_xor(a, off, 64);
                b += __shfl_xor(b, off, 64);
            }
            s1[mi][j] = a; s2[mi][j] = b;
        }
    if (cc == 0) {
        #pragma unroll
        for (int mi = 0; mi < 4; mi++)
            #pragma unroll
            for (int j = 0; j < 4; j++) {
                int lr = wr + mi * 16 + cr0 + j;
                red[lr][wv & 1][0] = s1[mi][j];
                red[lr][wv & 1][1] = s2[mi][j];
            }
    }
    __syncthreads();
    #pragma unroll
    for (int mi = 0; mi < 4; mi++)
        #pragma unroll
        for (int ni = 0; ni < 4; ni++) {
            int col = wc + ni * 16 + cc;
            float ls = lnS[col], lb = lnB[col];
            #pragma unroll
            for (int j = 0; j < 4; j++) {
                int lr = wr + mi * 16 + cr0 + j;
                float tot  = red[lr][0][0] + red[lr][1][0];
                float tot2 = red[lr][0][1] + red[lr][1][1];
                float mean = tot * (1.f / 128.f);
                float var  = tot2 * (1.f / 128.f) - mean * mean;
                float inv  = rsqrtf(var + 1e-5f);
                outp[(long long)(m0 + lr) * 128 + col] =
                    f2b((acc[mi][ni][j] - mean) * inv * ls + lb);
            }
        }
}

// ---------------------------------------------------------------------------
// scores GEMM with split B source (R15-verified).
// ---------------------------------------------------------------------------
__global__ __launch_bounds__(256) void gemm_scores(
    const bf* __restrict__ A,    // cp [512][256]
    const bf* __restrict__ B1,   // item [NN][128]
    const bf* __restrict__ B2,   // nf   [NN][128]
    float* __restrict__ outp)    // [512][NN]
{
    __shared__ bf As[128][40];
    __shared__ bf Bs[128][40];
    const int tid = threadIdx.x;
    const int tm = blockIdx.x / 94, tn = blockIdx.x - tm * 94;
    const int m0 = tm * 128;
    const int n0 = tn * 128;
    const int lane = tid & 63;
    const int wv = tid >> 6;
    const int wr = (wv >> 1) * 64, wc = (wv & 1) * 64;
    const int fr = lane & 15;
    const int kq = (lane >> 4) * 8;
    const int sr = tid >> 2, scol = (tid & 3) * 8;
    f32x4 acc[4][4] = {};

    for (int k0 = 0; k0 < 256; k0 += 32) {
        short8 va0 = ld8<false>(A, (long long)(m0 + sr) * 256 + k0 + scol);
        short8 va1 = ld8<false>(A, (long long)(m0 + sr + 64) * 256 + k0 + scol);
        const int gk = k0 + scol;
        const bf* bb = (gk < 128) ? B1 : B2;
        const int kk = gk & 127;
        short8 vb0 = {0,0,0,0,0,0,0,0}, vb1 = {0,0,0,0,0,0,0,0};
        if (n0 + sr < NN)      vb0 = *(const short8*)(bb + (long long)(n0 + sr) * 128 + kk);
        if (n0 + sr + 64 < NN) vb1 = *(const short8*)(bb + (long long)(n0 + sr + 64) * 128 + kk);
        *(short8*)&As[sr][scol] = va0;
        *(short8*)&As[sr + 64][scol] = va1;
        *(short8*)&Bs[sr][scol] = vb0;
        *(short8*)&Bs[sr + 64][scol] = vb1;
        __syncthreads();
        bf16x8 af[4], bfg[4];
        #pragma unroll
        for (int i = 0; i < 4; i++) af[i]  = *(const bf16x8*)&As[wr + i * 16 + fr][kq];
        #pragma unroll
        for (int i = 0; i < 4; i++) bfg[i] = *(const bf16x8*)&Bs[wc + i * 16 + fr][kq];
        #pragma unroll
        for (int mi = 0; mi < 4; mi++)
            #pragma unroll
            for (int ni = 0; ni < 4; ni++)
                acc[mi][ni] = __builtin_amdgcn_mfma_f32_16x16x32_bf16(
                    af[mi], bfg[ni], acc[mi][ni], 0, 0, 0);
        __syncthreads();
    }

    const int cr0 = (lane >> 4) * 4;
    const int cc = lane & 15;
    #pragma unroll
    for (int mi = 0; mi < 4; mi++) {
        #pragma unroll
        for (int ni = 0; ni < 4; ni++) {
            int col = n0 + wc + ni * 16 + cc;
            if (col >= NN) continue;
            #pragma unroll
            for (int j = 0; j < 4; j++) {
                int row = m0 + wr + mi * 16 + cr0 + j;
                outp[(long long)row * NN + col] = acc[mi][ni][j];
            }
        }
    }
}

// all 4 GCN weight transposes in one dispatch
__global__ __launch_bounds__(256) void transpose4_k(
    const float* s0, const float* s1, const float* s2, const float* s3,
    bf* d0, bf* d1, bf* d2, bf* d3)
{
    __shared__ bf t[32][33];
    const int z = blockIdx.z;
    const float* in = (z == 0) ? s0 : (z == 1) ? s1 : (z == 2) ? s2 : s3;
    bf* out = (z == 0) ? d0 : (z == 1) ? d1 : (z == 2) ? d2 : d3;
    const int R = (z & 1) ? HIDC : DD;
    const int C = (z & 1) ? DD : HIDC;
    int r0 = blockIdx.x * 32, c0 = blockIdx.y * 32;
    if (r0 >= R || c0 >= C) return;
    int tx = threadIdx.x, ty = threadIdx.y;   // 32 x 8
    #pragma unroll
    for (int i = 0; i < 4; i++) {
        int r = r0 + ty + i * 8, c = c0 + tx;
        bf v = f2b(0.f);
        if (r < R && c < C) v = f2b(in[(long long)r * C + c]);
        t[ty + i * 8][tx] = v;
    }
    __syncthreads();
    #pragma unroll
    for (int i = 0; i < 4; i++) {
        int c = c0 + ty + i * 8, r = r0 + tx;
        if (c < C && r < R) out[(long long)c * R + r] = t[tx][ty + i * 8];
    }
}

template<bool IN_F32>
__global__ __launch_bounds__(256) void transpose_k(
    const void* __restrict__ in, int ldin, long long sI1, long long sI2, int zdiv,
    const float* __restrict__ mulp, int ldmul,
    bf* __restrict__ outp, int ldout, long long sOut,
    int R, int C)
{
    __shared__ bf t[32][33];
    const int z = blockIdx.z;
    const int zq = z / zdiv, zr = z - zq * zdiv;
    const long long offI = (long long)zq * sI1 + (long long)zr * sI2;
    bf* op = outp + (long long)z * sOut;
    int r0 = blockIdx.x * 32, c0 = blockIdx.y * 32;
    int tx = threadIdx.x, ty = threadIdx.y;   // 32 x 8
    #pragma unroll
    for (int i = 0; i < 4; i++) {
        int r = r0 + ty + i * 8, c = c0 + tx;
        bf v = f2b(0.f);
        if (r < R && c < C) {
            v = ldelem<IN_F32>(in, offI + (long long)r * ldin + c);
            if (mulp) v = f2b(b2f(v) * mulp[(long long)r * ldmul + c]);
        }
        t[ty + i * 8][tx] = v;
    }
    __syncthreads();
    #pragma unroll
    for (int i = 0; i < 4; i++) {
        int c = c0 + ty + i * 8, r = r0 + tx;
        if (c < C && r < R) op[(long long)c * ldout + r] = t[tx][ty + i * 8];
    }
}

__global__ __launch_bounds__(256) void reduceK(
    const float* __restrict__ part, const float* __restrict__ bias,
    bf* __restrict__ outp, int total, int nz, long long zs)
{
    int i = blockIdx.x * 256 + threadIdx.x;
    if (i >= total) return;
    float s = 0.f;
    for (int zz = 0; zz < nz; zz++) s += part[(long long)zz * zs + i];
    if (bias) s += bias[i & 127];
    outp[i] = f2b(s);
}

__global__ __launch_bounds__(256) void softmax512(bf* __restrict__ S, int nrows)
{
    int gid = blockIdx.x * 256 + threadIdx.x;
    int wid = gid >> 6, lane = gid & 63;
    if (wid >= nrows) return;
    bf* row = S + (long long)wid * 512;
    short8 raw = *(const short8*)&row[lane * 8];
    float v[8];
    float mx = -3.0e38f;
    #pragma unroll
    for (int j = 0; j < 8; j++) {
        v[j] = us2f((unsigned short)raw[j]);
        mx = fmaxf(mx, v[j]);
    }
    #pragma unroll
    for (int off = 32; off; off >>= 1) mx = fmaxf(mx, __shfl_xor(mx, off, 64));
    float sum = 0.f;
    #pragma unroll
    for (int j = 0; j < 8; j++) { v[j] = __expf(v[j] - mx); sum += v[j]; }
    #pragma unroll
    for (int off = 32; off; off >>= 1) sum += __shfl_xor(sum, off, 64);
    float inv = 1.f / sum;
    short8 o;
    #pragma unroll
    for (int j = 0; j < 8; j++) o[j] = (short)f2us(v[j] * inv);
    *(short8*)&row[lane * 8] = o;
}

__global__ __launch_bounds__(256) void build_citing(
    const bf* __restrict__ x2, const bf* __restrict__ nf,
    const int* __restrict__ citing, bf* __restrict__ cp)
{
    int i = blockIdx.x * 256 + threadIdx.x;
    if (i >= BBATCH * 256) return;
    int b = i >> 8, d = i & 255;
    float v;
    if (d < 128) {
        float s = 0.f;
        for (int l = 0; l < LSEQ; l++)
            s += b2f(x2[((long long)b * LSEQ + l) * 128 + d]);
        v = s * (1.f / (float)LSEQ);
    } else {
        v = b2f(nf[(long long)citing[b] * 128 + (d - 128)]);
    }
    cp[i] = f2b(v);
}

// ---------------------------------------------------------------------------
extern "C" void kernel_launch(void* const* d_in, const int* in_sizes, int n_in,
                              void* d_out, int out_size, void* d_ws, size_t ws_size,
                              hipStream_t stream)
{
    const float* emb  = (const float*)d_in[0];
    const float* f1w  = (const float*)d_in[1];
    const float* f1b  = (const float*)d_in[2];
    const float* g0w1 = (const float*)d_in[3];  const float* g0b1 = (const float*)d_in[4];
    const float* g0w2 = (const float*)d_in[5];  const float* g0b2 = (const float*)d_in[6];
    const float* g1w1 = (const float*)d_in[7];  const float* g1b1 = (const float*)d_in[8];
    const float* g1w2 = (const float*)d_in[9];  const float* g1b2 = (const float*)d_in[10];
    const float* ipw  = (const float*)d_in[11]; const float* ipb  = (const float*)d_in[12];
    const float* opw  = (const float*)d_in[13]; const float* opb  = (const float*)d_in[14];
    const float* ln1s = (const float*)d_in[15]; const float* ln1b = (const float*)d_in[16];
    const float* ff1w = (const float*)d_in[17]; const float* ff1b = (const float*)d_in[18];
    const float* ff2w = (const float*)d_in[19]; const float* ff2b = (const float*)d_in[20];
    const float* ln2s = (const float*)d_in[21]; const float* ln2b = (const float*)d_in[22];
    const float* adj  = (const float*)d_in[23];
    const float* nfe  = (const float*)d_in[24];
    const int* citing = (const int*)d_in[26];
    const int* useqs  = (const int*)d_in[28];
    float* outp = (float*)d_out;

    size_t off = 0;
    auto carve = [&](size_t bytes) -> char* {
        char* p = (char*)d_ws + off;
        off += (bytes + 255) & ~(size_t)255;
        return p;
    };
    bf* adjb = (bf*)carve((size_t)NN * NN * 2);       // bf16 copy of adj (288 MB)
    bf* nf   = (bf*)carve((size_t)NN * DD * 2);
    bf* bufP = (bf*)carve((size_t)NN * DD * 2);
    bf* bufQ = (bf*)carve((size_t)NN * DD * 2);
    bf* BT   = (bf*)carve((size_t)NN * DD * 2);       // transposed [128][12000]
    bf* Hbuf = (bf*)carve((size_t)NN * HIDC * 2);
    float* part = (float*)carve((size_t)AZ * NN * DD * 4);   // 30 MB
    bf* qkv  = (bf*)carve((size_t)10240 * 384 * 2);
    bf* Sb   = (bf*)carve((size_t)80 * 512 * 512 * 2);
    bf* w10T = (bf*)carve((size_t)DD * HIDC * 2);
    bf* w20T = (bf*)carve((size_t)DD * HIDC * 2);
    bf* w11T = (bf*)carve((size_t)DD * HIDC * 2);
    bf* w21T = (bf*)carve((size_t)DD * HIDC * 2);
    // aliases (regions dead by the time these are live)
    bf* x1ln = (bf*)Hbuf;
    bf* cp   = (bf*)((char*)Hbuf + (size_t)10240 * DD * 2);
    char* pr = (char*)part;
    bf* VT   = (bf*)pr; pr += (size_t)80 * 32 * 512 * 2;
    bf* o_   = (bf*)pr; pr += (size_t)10240 * DD * 2;
    bf* ffh  = (bf*)pr; pr += (size_t)10240 * FFDIM * 2;
    bf* x2   = (bf*)pr; pr += (size_t)10240 * DD * 2;

    dim3 tb(256), tb512(512), tt(32, 8);
    const long long NM = (long long)NN * DD;   // 1,536,000

    // all 4 GCN weight transposes in one dispatch
    transpose4_k<<<dim3(8, 8, 4), tt, 0, stream>>>(
        g0w1, g0w2, g1w1, g1w2, w10T, w20T, w11T, w21T);

    // nf = node_feature @ f1_w^T + f1_b    [12000,128]
    gemm128<true, true, true, false, false, false><<<dim3(94, 1), tb, 0, stream>>>(
        nfe, FFEAT, 0, 0, f1w, FFEAT, 0, 0, f1b,
        nf, DD, 0, 0, NN, DD, FFEAT, 1, 1, 1.f, nullptr);
    // BT = (emb .* nf)^T   [128][12000]
    transpose_k<false><<<dim3(375, 4, 1), tt, 0, stream>>>(nf, DD, 0, 0, 1, emb, DD, BT, NN, 0, NN, DD);

    const float* biases1[2] = { g0b1, g1b1 };
    const bf* w1T[2] = { w10T, w11T };
    const bf* w2T[2] = { w20T, w21T };

    for (int g = 0; g < 2; g++) {
        // t = A @ x  (x^T in BT), K-split 5
        if (g == 0) {
            gemm128<true, false, false, false, true, true><<<dim3(94, AZ), tb, 0, stream>>>(
                adj, NN, AKS, 0, BT, NN, AKS, 0, nullptr,
                part, DD, NM, 0, NN, DD, AKS, 1, 1, 1.f, adjb);
        } else {
            adj_gemm8<<<dim3(94, AZ), tb512, 0, stream>>>(adjb, BT, part);
        }
        bf* tbuf = (g == 0) ? bufP : bufQ;
        reduceK<<<dim3((NM + 255) / 256), tb, 0, stream>>>(part, nullptr, tbuf, (int)NM, AZ, NM);
        // h = relu(t @ W1 + b1)   [12000,256]
        gemm128<false, false, true, true, false, false><<<dim3(188, 1), tb, 0, stream>>>(
            tbuf, DD, 0, 0, w1T[g], DD, 0, 0, biases1[g],
            Hbuf, HIDC, 0, 0, NN, HIDC, DD, 2, 1, 1.f, nullptr);
        // BT = (h @ W2)^T  directly
        gemm_t2<<<dim3(94), tb, 0, stream>>>(Hbuf, w2T[g], BT);
        // x' = A @ t2 + b2
        adj_gemm8<<<dim3(94, AZ), tb512, 0, stream>>>(adjb, BT, part);
        if (g == 0) {
            reduceKT<<<dim3(375, 4), tt, 0, stream>>>(part, g0b2, BT);
        } else {
            reduceK<<<dim3((NM + 255) / 256), tb, 0, stream>>>(part, g1b2, bufQ, (int)NM, AZ, NM);
        }
    }
    bf* item = bufQ;

    // qkv = item[u_seqs] @ in_proj_w^T + b   (gathered A, replaces gather_rows+seq)
    gemm_qkv<<<dim3(240), tb, 0, stream>>>(item, useqs, ipw, ipb, qkv);
    // VT[z=(n,h)][d][t] from qkv V slice
    transpose_k<false><<<dim3(16, 1, 80), tt, 0, stream>>>(
        qkv + 256, 7680, 384, 32, 4, nullptr, 0, VT, 512, 16384, 512, 32);
    // S[z] = alpha * Q_z @ K_z^T   (z = n*4+h), M=N=512, K=32
    gemm128<false, false, false, false, false, false><<<dim3(16, 80), tb, 0, stream>>>(
        qkv, 7680, 384, 32, qkv + 128, 7680, 384, 32, nullptr,
        Sb, 512, (long long)4 * 262144, 262144, 512, 512, 32, 4, 4, 0.17677669529663687f, nullptr);
    // softmax rows (in place)
    softmax512<<<dim3(10240), tb, 0, stream>>>(Sb, 80 * 512);
    // o = P @ V   -> o[s][n][h*32+d]
    gemm128<false, false, false, false, false, false><<<dim3(4, 80), tb, 0, stream>>>(
        Sb, 512, (long long)4 * 262144, 262144, VT, 512, (long long)4 * 16384, 16384, nullptr,
        o_, 2560, 128, 32, 512, 32, 512, 1, 4, 1.f, nullptr);
    // x1 = LN(item[u_seqs] + o @ out_proj^T + b)   (gathered residual)
    gemm_ln<<<dim3(80), tb, 0, stream>>>(o_, DD, opw, opb, item, useqs, ln1s, ln1b, x1ln, DD);
    // ffh = relu(x1 @ ff1^T + b)   [10240,512]
    gemm128<false, true, true, true, false, false><<<dim3(320, 1), tb, 0, stream>>>(
        x1ln, DD, 0, 0, ff1w, DD, 0, 0, ff1b,
        ffh, FFDIM, 0, 0, 10240, FFDIM, DD, 4, 1, 1.f, nullptr);
    // x2 = LN(x1 + ffh @ ff2^T + b)
    gemm_ln<<<dim3(80), tb, 0, stream>>>(ffh, FFDIM, ff2w, ff2b, x1ln, nullptr, ln2s, ln2b, x2, FFDIM);
    // citing_paper
    build_citing<<<dim3(512), tb, 0, stream>>>(x2, nf, citing, cp);
    // scores = cp @ [item|nf]^T   [512,12000]  (f32 out, split-B)
    gemm_scores<<<dim3(376), tb, 0, stream>>>(cp, item, nf, outp);
}

// Round 19
// 716.004 us; speedup vs baseline: 1.0278x; 1.0278x over previous
//
#include <hip/hip_runtime.h>
#include <hip/hip_bf16.h>

typedef __hip_bfloat16 bf;
typedef __attribute__((ext_vector_type(4))) float f32x4;
typedef __attribute__((ext_vector_type(8))) __bf16 bf16x8;
typedef __attribute__((ext_vector_type(8))) short short8;
typedef __attribute__((ext_vector_type(4))) short short4v;

#define NN 12000
#define DD 128
#define HIDC 256
#define BBATCH 512
#define LSEQ 20
#define FFEAT 400
#define FFDIM 512
#define AZ 5
#define AKS (NN / AZ)     // 2400 = 37*64 + 32

__device__ __forceinline__ float b2f(bf v) { return __bfloat162float(v); }
__device__ __forceinline__ bf f2b(float v) { return __float2bfloat16(v); }
__device__ __forceinline__ float us2f(unsigned short u) {
    return __uint_as_float(((unsigned int)u) << 16);
}
__device__ __forceinline__ unsigned short f2us(float f) {
    bf h = __float2bfloat16(f);
    return __builtin_bit_cast(unsigned short, h);
}

__device__ __forceinline__ void gload_lds16(const bf* g, bf* l) {
    __builtin_amdgcn_global_load_lds(
        (__attribute__((address_space(1))) void*)(g),
        (__attribute__((address_space(3))) void*)(l),
        16, 0, 0);
}

template<bool F32>
__device__ __forceinline__ short8 ld8(const void* p, long long idx) {
    if (F32) {
        const float* fp = (const float*)p + idx;
        f32x4 u0 = *(const f32x4*)fp;
        f32x4 u1 = *(const f32x4*)(fp + 4);
        short8 s;
        s[0] = (short)f2us(u0[0]); s[1] = (short)f2us(u0[1]);
        s[2] = (short)f2us(u0[2]); s[3] = (short)f2us(u0[3]);
        s[4] = (short)f2us(u1[0]); s[5] = (short)f2us(u1[1]);
        s[6] = (short)f2us(u1[2]); s[7] = (short)f2us(u1[3]);
        return s;
    } else {
        return *(const short8*)((const bf*)p + idx);
    }
}

template<bool F32>
__device__ __forceinline__ bf ldelem(const void* p, long long idx) {
    if (F32) return f2b(((const float*)p)[idx]);
    return ((const bf*)p)[idx];
}

// ---------------------------------------------------------------------------
// adj pass v8 (R13 best): BK=64, 4-buffer ring, prefetch 3, one barrier/step.
// ---------------------------------------------------------------------------
__global__ __launch_bounds__(512) void adj_gemm8(
    const bf* __restrict__ A,    // adjb [NN][NN]
    const bf* __restrict__ Bt,   // BT [128][NN]
    float* __restrict__ part)    // [AZ][NN][128]
{
    alignas(16) __shared__ bf As[4][128 * 64];
    alignas(16) __shared__ bf Bs[4][128 * 64];
    const int tid = threadIdx.x;
    const int lane = tid & 63;
    const int w = tid >> 6;                       // 0..7
    const int z = blockIdx.y;
    const long long k0 = (long long)z * AKS;
    int m0 = blockIdx.x * 128;
    if (m0 > NN - 128) m0 = NN - 128;

    const int rowi = lane >> 3;
    const int chks = (lane & 7) ^ rowi;
    const bf* gA[2]; const bf* gB[2]; int lo[2];
    #pragma unroll
    for (int i = 0; i < 2; i++) {
        int rbase = 16 * w + 8 * i;
        gA[i] = A  + (long long)(m0 + rbase + rowi) * NN + k0 + chks * 8;
        gB[i] = Bt + (long long)(rbase + rowi) * NN + k0 + chks * 8;
        lo[i] = rbase * 64;
    }
    const int rowiT = lane >> 2;
    const int chksT = (lane & 3) ^ ((lane >> 3) & 3);
    const bf* gAT = A  + (long long)(m0 + 16 * w + rowiT) * NN + k0 + 2368 + chksT * 8;
    const bf* gBT = Bt + (long long)(16 * w + rowiT) * NN + k0 + 2368 + chksT * 8;
    const int loT = (16 * w) * 32;

    const int wr = (w >> 1) * 32, wc = (w & 1) * 64;
    const int fr = lane & 15;
    const int kq = lane >> 4;
    int aoff[2][2], boff[2][4], aoffT[2], boffT[4];
    #pragma unroll
    for (int mi = 0; mi < 2; mi++) {
        int ra = wr + mi * 16 + fr;
        aoff[0][mi] = ra * 64 + ((kq)     ^ (ra & 7)) * 8;
        aoff[1][mi] = ra * 64 + ((4 + kq) ^ (ra & 7)) * 8;
        aoffT[mi]   = ra * 32 + (kq ^ ((ra >> 1) & 3)) * 8;
    }
    #pragma unroll
    for (int ni = 0; ni < 4; ni++) {
        int rb = wc + ni * 16 + fr;
        boff[0][ni] = rb * 64 + ((kq)     ^ (rb & 7)) * 8;
        boff[1][ni] = rb * 64 + ((4 + kq) ^ (rb & 7)) * 8;
        boffT[ni]   = rb * 32 + (kq ^ ((rb >> 1) & 3)) * 8;
    }
    f32x4 acc[2][4] = {};

    auto stage64 = [&](int t, int b) {
        const long long go = (long long)t * 64;
        const int bo = b * (128 * 64);
        #pragma unroll
        for (int i = 0; i < 2; i++) {
            gload_lds16(gA[i] + go, &As[0][0] + bo + lo[i]);
            gload_lds16(gB[i] + go, &Bs[0][0] + bo + lo[i]);
        }
    };
    auto stageTail = [&]() {
        gload_lds16(gAT, &As[1][0] + loT);
        gload_lds16(gBT, &Bs[1][0] + loT);
    };
    auto compute64 = [&](int b) {
        const bf* Ab = &As[0][0] + b * (128 * 64);
        const bf* Bb = &Bs[0][0] + b * (128 * 64);
        #pragma unroll
        for (int s = 0; s < 2; s++) {
            bf16x8 af[2], bfr[4];
            #pragma unroll
            for (int mi = 0; mi < 2; mi++) af[mi]  = *(const bf16x8*)(Ab + aoff[s][mi]);
            #pragma unroll
            for (int ni = 0; ni < 4; ni++) bfr[ni] = *(const bf16x8*)(Bb + boff[s][ni]);
            #pragma unroll
            for (int mi = 0; mi < 2; mi++)
                #pragma unroll
                for (int ni = 0; ni < 4; ni++)
                    acc[mi][ni] = __builtin_amdgcn_mfma_f32_16x16x32_bf16(
                        af[mi], bfr[ni], acc[mi][ni], 0, 0, 0);
        }
    };

    stage64(0, 0);
    stage64(1, 1);
    stage64(2, 2);

    #pragma unroll 1
    for (int t = 0; t < 35; t++) {
        asm volatile("s_waitcnt vmcnt(8)" ::: "memory");
        __builtin_amdgcn_s_barrier();
        __builtin_amdgcn_sched_barrier(0);
        compute64(t & 3);
        if (t < 34) stage64(t + 3, (t + 3) & 3);
        else        stageTail();
    }
    asm volatile("s_waitcnt vmcnt(6)" ::: "memory");
    __builtin_amdgcn_s_barrier();
    __builtin_amdgcn_sched_barrier(0);
    compute64(3);
    asm volatile("s_waitcnt vmcnt(2)" ::: "memory");
    __builtin_amdgcn_s_barrier();
    __builtin_amdgcn_sched_barrier(0);
    compute64(0);
    asm volatile("s_waitcnt vmcnt(0)" ::: "memory");
    __builtin_amdgcn_s_barrier();
    __builtin_amdgcn_sched_barrier(0);
    {
        bf16x8 af[2], bfr[4];
        #pragma unroll
        for (int mi = 0; mi < 2; mi++) af[mi]  = *(const bf16x8*)(&As[1][0] + aoffT[mi]);
        #pragma unroll
        for (int ni = 0; ni < 4; ni++) bfr[ni] = *(const bf16x8*)(&Bs[1][0] + boffT[ni]);
        #pragma unroll
        for (int mi = 0; mi < 2; mi++)
            #pragma unroll
            for (int ni = 0; ni < 4; ni++)
                acc[mi][ni] = __builtin_amdgcn_mfma_f32_16x16x32_bf16(
                    af[mi], bfr[ni], acc[mi][ni], 0, 0, 0);
    }

    float* C = part + (long long)z * ((long long)NN * 128);
    const int cr0 = (lane >> 4) * 4;
    const int cc = lane & 15;
    #pragma unroll
    for (int mi = 0; mi < 2; mi++) {
        #pragma unroll
        for (int ni = 0; ni < 4; ni++) {
            int col = wc + ni * 16 + cc;
            #pragma unroll
            for (int j = 0; j < 4; j++) {
                int row = m0 + wr + mi * 16 + cr0 + j;
                C[(long long)row * 128 + col] = acc[mi][ni][j];
            }
        }
    }
}

// ---------------------------------------------------------------------------
// Generic batched MFMA GEMM: C = act(alpha * A @ B^T + bias)
// ---------------------------------------------------------------------------
template<bool A_F32, bool B_F32, bool HAS_BIAS, bool RELU, bool OUT_F32, bool SIDE_A>
__global__ __launch_bounds__(256) void gemm128(
    const void* __restrict__ A, int lda, long long sA1, long long sA2,
    const void* __restrict__ Bm, int ldb, long long sB1, long long sB2,
    const float* __restrict__ bias,
    void* __restrict__ Cv, int ldc, long long sC1, long long sC2,
    int M, int N, int K, int tilesN, int zdiv, float alpha,
    bf* __restrict__ sideA)
{
    __shared__ bf As[128][40];
    __shared__ bf Bs[128][40];
    const int tid = threadIdx.x;
    const int z = blockIdx.y;
    const int zq = z / zdiv, zr = z - zq * zdiv;
    const char* Ap = (const char*)A;
    const char* Bp = (const char*)Bm;
    const long long offA = (long long)zq * sA1 + (long long)zr * sA2;
    const long long offB = (long long)zq * sB1 + (long long)zr * sB2;
    const long long offC = (long long)zq * sC1 + (long long)zr * sC2;
    const int tm = blockIdx.x / tilesN, tn = blockIdx.x - tm * tilesN;
    int m0 = tm * 128; if (m0 > M - 128) m0 = M - 128;
    const int n0 = tn * 128;
    const int lane = tid & 63;
    const int wv = tid >> 6;
    const int wr = (wv >> 1) * 64, wc = (wv & 1) * 64;
    const int fr = lane & 15;
    const int kq = (lane >> 4) * 8;
    const int sr = tid >> 2, scol = (tid & 3) * 8;
    f32x4 acc[4][4] = {};

    for (int k0 = 0; k0 < K; k0 += 32) {
        if (k0 + 32 <= K) {
            const long long ia0 = offA + (long long)(m0 + sr) * lda + k0 + scol;
            const long long ia1 = offA + (long long)(m0 + sr + 64) * lda + k0 + scol;
            short8 va0 = ld8<A_F32>(Ap, ia0);
            short8 va1 = ld8<A_F32>(Ap, ia1);
            short8 vb0 = {0,0,0,0,0,0,0,0}, vb1 = {0,0,0,0,0,0,0,0};
            if (n0 + sr < N)      vb0 = ld8<B_F32>(Bp, offB + (long long)(n0 + sr) * ldb + k0 + scol);
            if (n0 + sr + 64 < N) vb1 = ld8<B_F32>(Bp, offB + (long long)(n0 + sr + 64) * ldb + k0 + scol);
            if (SIDE_A) {
                *(short8*)&sideA[ia0] = va0;
                *(short8*)&sideA[ia1] = va1;
            }
            *(short8*)&As[sr][scol] = va0;
            *(short8*)&As[sr + 64][scol] = va1;
            *(short8*)&Bs[sr][scol] = vb0;
            *(short8*)&Bs[sr + 64][scol] = vb1;
        } else {
            bf zv = f2b(0.f);
            for (int i = tid; i < 128 * 32; i += 256) {
                int r = i >> 5, c = i & 31, gk = k0 + c;
                As[r][c] = (gk < K) ? ldelem<A_F32>(Ap, offA + (long long)(m0 + r) * lda + gk) : zv;
                Bs[r][c] = (gk < K && n0 + r < N) ? ldelem<B_F32>(Bp, offB + (long long)(n0 + r) * ldb + gk) : zv;
            }
        }
        __syncthreads();
        bf16x8 af[4], bfg[4];
        #pragma unroll
        for (int i = 0; i < 4; i++) af[i]  = *(const bf16x8*)&As[wr + i * 16 + fr][kq];
        #pragma unroll
        for (int i = 0; i < 4; i++) bfg[i] = *(const bf16x8*)&Bs[wc + i * 16 + fr][kq];
        #pragma unroll
        for (int mi = 0; mi < 4; mi++)
            #pragma unroll
            for (int ni = 0; ni < 4; ni++)
                acc[mi][ni] = __builtin_amdgcn_mfma_f32_16x16x32_bf16(
                    af[mi], bfg[ni], acc[mi][ni], 0, 0, 0);
        __syncthreads();
    }

    const int cr0 = (lane >> 4) * 4;
    const int cc = lane & 15;
    #pragma unroll
    for (int mi = 0; mi < 4; mi++) {
        #pragma unroll
        for (int ni = 0; ni < 4; ni++) {
            int col = n0 + wc + ni * 16 + cc;
            if (col >= N) continue;
            float bv = 0.f;
            if (HAS_BIAS) bv = bias[col];
            #pragma unroll
            for (int j = 0; j < 4; j++) {
                int row = m0 + wr + mi * 16 + cr0 + j;
                float v = acc[mi][ni][j] * alpha + bv;
                if (RELU) v = fmaxf(v, 0.f);
                if (OUT_F32) ((float*)Cv)[offC + (long long)row * ldc + col] = v;
                else ((bf*)Cv)[offC + (long long)row * ldc + col] = f2b(v);
            }
        }
    }
}

// ---------------------------------------------------------------------------
// nf GEMM with fused BT write: nf = node_feature @ f1w^T + f1b (row-major)
// AND BT[col][row] = bf16(b2f(nf_bf16) * emb[row][col]) via short4 column
// chunks (gemm_t2 pattern; N=128 single tile, bit-identical to the old
// separate transpose which read rounded bf16 nf and f32 emb).
// ---------------------------------------------------------------------------
__global__ __launch_bounds__(256) void gemm_nf(
    const float* __restrict__ A,     // node_feature [NN][400]
    const float* __restrict__ Bw,    // f1w [128][400]
    const float* __restrict__ bias,  // f1b [128]
    const float* __restrict__ emb,   // [NN][128] f32
    bf* __restrict__ nfp,            // [NN][128]
    bf* __restrict__ BT)             // [128][NN]
{
    __shared__ bf As[128][40];
    __shared__ bf Bs[128][40];
    const int tid = threadIdx.x;
    int m0 = blockIdx.x * 128;
    if (m0 > NN - 128) m0 = NN - 128;   // overlap rows: identical writes
    const int lane = tid & 63;
    const int wv = tid >> 6;
    const int wr = (wv >> 1) * 64, wc = (wv & 1) * 64;
    const int fr = lane & 15;
    const int kq = (lane >> 4) * 8;
    const int sr = tid >> 2, scol = (tid & 3) * 8;
    f32x4 acc[4][4] = {};

    for (int k0 = 0; k0 < FFEAT; k0 += 32) {
        if (k0 + 32 <= FFEAT) {
            *(short8*)&As[sr][scol]      = ld8<true>(A, (long long)(m0 + sr) * FFEAT + k0 + scol);
            *(short8*)&As[sr + 64][scol] = ld8<true>(A, (long long)(m0 + sr + 64) * FFEAT + k0 + scol);
            *(short8*)&Bs[sr][scol]      = ld8<true>(Bw, (long long)sr * FFEAT + k0 + scol);
            *(short8*)&Bs[sr + 64][scol] = ld8<true>(Bw, (long long)(sr + 64) * FFEAT + k0 + scol);
        } else {
            bf zv = f2b(0.f);
            for (int i = tid; i < 128 * 32; i += 256) {
                int r = i >> 5, c = i & 31, gk = k0 + c;
                As[r][c] = (gk < FFEAT) ? f2b(A[(long long)(m0 + r) * FFEAT + gk]) : zv;
                Bs[r][c] = (gk < FFEAT) ? f2b(Bw[(long long)r * FFEAT + gk]) : zv;
            }
        }
        __syncthreads();
        bf16x8 af[4], bfg[4];
        #pragma unroll
        for (int i = 0; i < 4; i++) af[i]  = *(const bf16x8*)&As[wr + i * 16 + fr][kq];
        #pragma unroll
        for (int i = 0; i < 4; i++) bfg[i] = *(const bf16x8*)&Bs[wc + i * 16 + fr][kq];
        #pragma unroll
        for (int mi = 0; mi < 4; mi++)
            #pragma unroll
            for (int ni = 0; ni < 4; ni++)
                acc[mi][ni] = __builtin_amdgcn_mfma_f32_16x16x32_bf16(
                    af[mi], bfg[ni], acc[mi][ni], 0, 0, 0);
        __syncthreads();
    }

    const int cr0 = (lane >> 4) * 4;
    const int cc = lane & 15;
    #pragma unroll
    for (int mi = 0; mi < 4; mi++) {
        #pragma unroll
        for (int ni = 0; ni < 4; ni++) {
            int col = wc + ni * 16 + cc;
            int rowb = m0 + wr + mi * 16 + cr0;   // 4-aligned
            float bv = bias[col];
            short4v tv;
            #pragma unroll
            for (int j = 0; j < 4; j++) {
                bf nv = f2b(acc[mi][ni][j] + bv);
                nfp[(long long)(rowb + j) * 128 + col] = nv;
                tv[j] = (short)f2us(b2f(nv) * emb[(long long)(rowb + j) * 128 + col]);
            }
            *(short4v*)&BT[(long long)col * NN + rowb] = tv;
        }
    }
}

// ---------------------------------------------------------------------------
// t2 GEMM with TRANSPOSED output (R16-verified).
// ---------------------------------------------------------------------------
__global__ __launch_bounds__(256) void gemm_t2(
    const bf* __restrict__ A,
    const bf* __restrict__ Bw,
    bf* __restrict__ BT)
{
    __shared__ bf As[128][40];
    __shared__ bf Bs[128][40];
    const int tid = threadIdx.x;
    int m0 = blockIdx.x * 128;
    if (m0 > NN - 128) m0 = NN - 128;
    const int lane = tid & 63;
    const int wv = tid >> 6;
    const int wr = (wv >> 1) * 64, wc = (wv & 1) * 64;
    const int fr = lane & 15;
    const int kq = (lane >> 4) * 8;
    const int sr = tid >> 2, scol = (tid & 3) * 8;
    f32x4 acc[4][4] = {};

    for (int k0 = 0; k0 < 256; k0 += 32) {
        *(short8*)&As[sr][scol]      = ld8<false>(A, (long long)(m0 + sr) * 256 + k0 + scol);
        *(short8*)&As[sr + 64][scol] = ld8<false>(A, (long long)(m0 + sr + 64) * 256 + k0 + scol);
        *(short8*)&Bs[sr][scol]      = ld8<false>(Bw, (long long)sr * 256 + k0 + scol);
        *(short8*)&Bs[sr + 64][scol] = ld8<false>(Bw, (long long)(sr + 64) * 256 + k0 + scol);
        __syncthreads();
        bf16x8 af[4], bfg[4];
        #pragma unroll
        for (int i = 0; i < 4; i++) af[i]  = *(const bf16x8*)&As[wr + i * 16 + fr][kq];
        #pragma unroll
        for (int i = 0; i < 4; i++) bfg[i] = *(const bf16x8*)&Bs[wc + i * 16 + fr][kq];
        #pragma unroll
        for (int mi = 0; mi < 4; mi++)
            #pragma unroll
            for (int ni = 0; ni < 4; ni++)
                acc[mi][ni] = __builtin_amdgcn_mfma_f32_16x16x32_bf16(
                    af[mi], bfg[ni], acc[mi][ni], 0, 0, 0);
        __syncthreads();
    }

    const int cr0 = (lane >> 4) * 4;
    const int cc = lane & 15;
    #pragma unroll
    for (int mi = 0; mi < 4; mi++) {
        #pragma unroll
        for (int ni = 0; ni < 4; ni++) {
            int col = wc + ni * 16 + cc;
            int rowb = m0 + wr + mi * 16 + cr0;
            short4v v;
            #pragma unroll
            for (int j = 0; j < 4; j++) v[j] = (short)f2us(acc[mi][ni][j]);
            *(short4v*)&BT[(long long)col * NN + rowb] = v;
        }
    }
}

// ---------------------------------------------------------------------------
// 5-way partial reduce + bias with transposed output (R16-verified).
// ---------------------------------------------------------------------------
__global__ __launch_bounds__(256) void reduceKT(
    const float* __restrict__ part, const float* __restrict__ bias,
    bf* __restrict__ BT)
{
    __shared__ bf t[32][33];
    const long long zs = (long long)NN * 128;
    int r0 = blockIdx.x * 32, c0 = blockIdx.y * 32;
    int tx = threadIdx.x, ty = threadIdx.y;   // 32 x 8
    #pragma unroll
    for (int i = 0; i < 4; i++) {
        int r = r0 + ty + i * 8, c = c0 + tx;
        float s = bias[c];
        #pragma unroll
        for (int z = 0; z < AZ; z++) s += part[(long long)z * zs + (long long)r * 128 + c];
        t[ty + i * 8][tx] = f2b(s);
    }
    __syncthreads();
    #pragma unroll
    for (int i = 0; i < 4; i++) {
        int c = c0 + ty + i * 8, r = r0 + tx;
        BT[(long long)c * NN + r] = t[tx][ty + i * 8];
    }
}

// ---------------------------------------------------------------------------
// GEMM with fused residual + LayerNorm epilogue (R15-verified).
// ---------------------------------------------------------------------------
__global__ __launch_bounds__(256) void gemm_ln(
    const bf* __restrict__ A, int lda,
    const float* __restrict__ Bw,
    const float* __restrict__ bias,
    const bf* __restrict__ resid,
    const float* __restrict__ lnS, const float* __restrict__ lnB,
    bf* __restrict__ outp, int K)
{
    __shared__ bf As[128][40];
    __shared__ bf Bs[128][40];
    __shared__ float red[128][2][2];
    const int tid = threadIdx.x;
    const int m0 = blockIdx.x * 128;
    const int lane = tid & 63;
    const int wv = tid >> 6;
    const int wr = (wv >> 1) * 64, wc = (wv & 1) * 64;
    const int fr = lane & 15;
    const int kq = (lane >> 4) * 8;
    const int sr = tid >> 2, scol = (tid & 3) * 8;
    f32x4 acc[4][4] = {};

    for (int k0 = 0; k0 < K; k0 += 32) {
        short8 va0 = ld8<false>(A, (long long)(m0 + sr) * lda + k0 + scol);
        short8 va1 = ld8<false>(A, (long long)(m0 + sr + 64) * lda + k0 + scol);
        short8 vb0 = ld8<true>(Bw, (long long)sr * K + k0 + scol);
        short8 vb1 = ld8<true>(Bw, (long long)(sr + 64) * K + k0 + scol);
        *(short8*)&As[sr][scol] = va0;
        *(short8*)&As[sr + 64][scol] = va1;
        *(short8*)&Bs[sr][scol] = vb0;
        *(short8*)&Bs[sr + 64][scol] = vb1;
        __syncthreads();
        bf16x8 af[4], bfg[4];
        #pragma unroll
        for (int i = 0; i < 4; i++) af[i]  = *(const bf16x8*)&As[wr + i * 16 + fr][kq];
        #pragma unroll
        for (int i = 0; i < 4; i++) bfg[i] = *(const bf16x8*)&Bs[wc + i * 16 + fr][kq];
        #pragma unroll
        for (int mi = 0; mi < 4; mi++)
            #pragma unroll
            for (int ni = 0; ni < 4; ni++)
                acc[mi][ni] = __builtin_amdgcn_mfma_f32_16x16x32_bf16(
                    af[mi], bfg[ni], acc[mi][ni], 0, 0, 0);
        __syncthreads();
    }

    const int cr0 = (lane >> 4) * 4;
    const int cc = lane & 15;
    #pragma unroll
    for (int mi = 0; mi < 4; mi++)
        #pragma unroll
        for (int ni = 0; ni < 4; ni++) {
            int col = wc + ni * 16 + cc;
            #pragma unroll
            for (int j = 0; j < 4; j++) {
                int row = m0 + wr + mi * 16 + cr0 + j;
                acc[mi][ni][j] += bias[col] + b2f(resid[(long long)row * 128 + col]);
            }
        }
    float s1[4][4], s2[4][4];
    #pragma unroll
    for (int mi = 0; mi < 4; mi++)
        #pragma unroll
        for (int j = 0; j < 4; j++) {
            float a = 0.f, b = 0.f;
            #pragma unroll
            for (int ni = 0; ni < 4; ni++) {
                float x = acc[mi][ni][j];
                a += x; b += x * x;
            }
            #pragma unroll
            for (int off = 1; off < 16; off <<= 1) {
                a += __shfl_xor(a, off, 64);
                b += __shfl_xor(b, off, 64);
            }
            s1[mi][j] = a; s2[mi][j] = b;
        }
    if (cc == 0) {
        #pragma unroll
        for (int mi = 0; mi < 4; mi++)
            #pragma unroll
            for (int j = 0; j < 4; j++) {
                int lr = wr + mi * 16 + cr0 + j;
                red[lr][wv & 1][0] = s1[mi][j];
                red[lr][wv & 1][1] = s2[mi][j];
            }
    }
    __syncthreads();
    #pragma unroll
    for (int mi = 0; mi < 4; mi++)
        #pragma unroll
        for (int ni = 0; ni < 4; ni++) {
            int col = wc + ni * 16 + cc;
            float ls = lnS[col], lb = lnB[col];
            #pragma unroll
            for (int j = 0; j < 4; j++) {
                int lr = wr + mi * 16 + cr0 + j;
                float tot  = red[lr][0][0] + red[lr][1][0];
                float tot2 = red[lr][0][1] + red[lr][1][1];
                float mean = tot * (1.f / 128.f);
                float var  = tot2 * (1.f / 128.f) - mean * mean;
                float inv  = rsqrtf(var + 1e-5f);
                outp[(long long)(m0 + lr) * 128 + col] =
                    f2b((acc[mi][ni][j] - mean) * inv * ls + lb);
            }
        }
}

// ---------------------------------------------------------------------------
// scores GEMM with split B source (R15-verified).
// ---------------------------------------------------------------------------
__global__ __launch_bounds__(256) void gemm_scores(
    const bf* __restrict__ A,    // cp [512][256]
    const bf* __restrict__ B1,   // item [NN][128]
    const bf* __restrict__ B2,   // nf   [NN][128]
    float* __restrict__ outp)    // [512][NN]
{
    __shared__ bf As[128][40];
    __shared__ bf Bs[128][40];
    const int tid = threadIdx.x;
    const int tm = blockIdx.x / 94, tn = blockIdx.x - tm * 94;
    const int m0 = tm * 128;
    const int n0 = tn * 128;
    const int lane = tid & 63;
    const int wv = tid >> 6;
    const int wr = (wv >> 1) * 64, wc = (wv & 1) * 64;
    const int fr = lane & 15;
    const int kq = (lane >> 4) * 8;
    const int sr = tid >> 2, scol = (tid & 3) * 8;
    f32x4 acc[4][4] = {};

    for (int k0 = 0; k0 < 256; k0 += 32) {
        short8 va0 = ld8<false>(A, (long long)(m0 + sr) * 256 + k0 + scol);
        short8 va1 = ld8<false>(A, (long long)(m0 + sr + 64) * 256 + k0 + scol);
        const int gk = k0 + scol;
        const bf* bb = (gk < 128) ? B1 : B2;
        const int kk = gk & 127;
        short8 vb0 = {0,0,0,0,0,0,0,0}, vb1 = {0,0,0,0,0,0,0,0};
        if (n0 + sr < NN)      vb0 = *(const short8*)(bb + (long long)(n0 + sr) * 128 + kk);
        if (n0 + sr + 64 < NN) vb1 = *(const short8*)(bb + (long long)(n0 + sr + 64) * 128 + kk);
        *(short8*)&As[sr][scol] = va0;
        *(short8*)&As[sr + 64][scol] = va1;
        *(short8*)&Bs[sr][scol] = vb0;
        *(short8*)&Bs[sr + 64][scol] = vb1;
        __syncthreads();
        bf16x8 af[4], bfg[4];
        #pragma unroll
        for (int i = 0; i < 4; i++) af[i]  = *(const bf16x8*)&As[wr + i * 16 + fr][kq];
        #pragma unroll
        for (int i = 0; i < 4; i++) bfg[i] = *(const bf16x8*)&Bs[wc + i * 16 + fr][kq];
        #pragma unroll
        for (int mi = 0; mi < 4; mi++)
            #pragma unroll
            for (int ni = 0; ni < 4; ni++)
                acc[mi][ni] = __builtin_amdgcn_mfma_f32_16x16x32_bf16(
                    af[mi], bfg[ni], acc[mi][ni], 0, 0, 0);
        __syncthreads();
    }

    const int cr0 = (lane >> 4) * 4;
    const int cc = lane & 15;
    #pragma unroll
    for (int mi = 0; mi < 4; mi++) {
        #pragma unroll
        for (int ni = 0; ni < 4; ni++) {
            int col = n0 + wc + ni * 16 + cc;
            if (col >= NN) continue;
            #pragma unroll
            for (int j = 0; j < 4; j++) {
                int row = m0 + wr + mi * 16 + cr0 + j;
                outp[(long long)row * NN + col] = acc[mi][ni][j];
            }
        }
    }
}

// all 4 GCN weight transposes in one dispatch
__global__ __launch_bounds__(256) void transpose4_k(
    const float* s0, const float* s1, const float* s2, const float* s3,
    bf* d0, bf* d1, bf* d2, bf* d3)
{
    __shared__ bf t[32][33];
    const int z = blockIdx.z;
    const float* in = (z == 0) ? s0 : (z == 1) ? s1 : (z == 2) ? s2 : s3;
    bf* out = (z == 0) ? d0 : (z == 1) ? d1 : (z == 2) ? d2 : d3;
    const int R = (z & 1) ? HIDC : DD;
    const int C = (z & 1) ? DD : HIDC;
    int r0 = blockIdx.x * 32, c0 = blockIdx.y * 32;
    if (r0 >= R || c0 >= C) return;
    int tx = threadIdx.x, ty = threadIdx.y;   // 32 x 8
    #pragma unroll
    for (int i = 0; i < 4; i++) {
        int r = r0 + ty + i * 8, c = c0 + tx;
        bf v = f2b(0.f);
        if (r < R && c < C) v = f2b(in[(long long)r * C + c]);
        t[ty + i * 8][tx] = v;
    }
    __syncthreads();
    #pragma unroll
    for (int i = 0; i < 4; i++) {
        int c = c0 + ty + i * 8, r = r0 + tx;
        if (c < C && r < R) out[(long long)c * R + r] = t[tx][ty + i * 8];
    }
}

template<bool IN_F32>
__global__ __launch_bounds__(256) void transpose_k(
    const void* __restrict__ in, int ldin, long long sI1, long long sI2, int zdiv,
    const float* __restrict__ mulp, int ldmul,
    bf* __restrict__ outp, int ldout, long long sOut,
    int R, int C)
{
    __shared__ bf t[32][33];
    const int z = blockIdx.z;
    const int zq = z / zdiv, zr = z - zq * zdiv;
    const long long offI = (long long)zq * sI1 + (long long)zr * sI2;
    bf* op = outp + (long long)z * sOut;
    int r0 = blockIdx.x * 32, c0 = blockIdx.y * 32;
    int tx = threadIdx.x, ty = threadIdx.y;   // 32 x 8
    #pragma unroll
    for (int i = 0; i < 4; i++) {
        int r = r0 + ty + i * 8, c = c0 + tx;
        bf v = f2b(0.f);
        if (r < R && c < C) {
            v = ldelem<IN_F32>(in, offI + (long long)r * ldin + c);
            if (mulp) v = f2b(b2f(v) * mulp[(long long)r * ldmul + c]);
        }
        t[ty + i * 8][tx] = v;
    }
    __syncthreads();
    #pragma unroll
    for (int i = 0; i < 4; i++) {
        int c = c0 + ty + i * 8, r = r0 + tx;
        if (c < C && r < R) op[(long long)c * ldout + r] = t[tx][ty + i * 8];
    }
}

__global__ __launch_bounds__(256) void reduceK(
    const float* __restrict__ part, const float* __restrict__ bias,
    bf* __restrict__ outp, int total, int nz, long long zs)
{
    int i = blockIdx.x * 256 + threadIdx.x;
    if (i >= total) return;
    float s = 0.f;
    for (int zz = 0; zz < nz; zz++) s += part[(long long)zz * zs + i];
    if (bias) s += bias[i & 127];
    outp[i] = f2b(s);
}

__global__ __launch_bounds__(256) void gather_rows(
    const bf* __restrict__ src, const int* __restrict__ idx,
    bf* __restrict__ dst, int nrows)
{
    int t = blockIdx.x * 256 + threadIdx.x;
    int row = t >> 4, p = t & 15;
    if (row >= nrows) return;
    long long srow = idx[row];
    *(short8*)&dst[(long long)row * 128 + p * 8] =
        *(const short8*)&src[srow * 128 + p * 8];
}

__global__ __launch_bounds__(256) void softmax512(bf* __restrict__ S, int nrows)
{
    int gid = blockIdx.x * 256 + threadIdx.x;
    int wid = gid >> 6, lane = gid & 63;
    if (wid >= nrows) return;
    bf* row = S + (long long)wid * 512;
    short8 raw = *(const short8*)&row[lane * 8];
    float v[8];
    float mx = -3.0e38f;
    #pragma unroll
    for (int j = 0; j < 8; j++) {
        v[j] = us2f((unsigned short)raw[j]);
        mx = fmaxf(mx, v[j]);
    }
    #pragma unroll
    for (int off = 32; off; off >>= 1) mx = fmaxf(mx, __shfl_xor(mx, off, 64));
    float sum = 0.f;
    #pragma unroll
    for (int j = 0; j < 8; j++) { v[j] = __expf(v[j] - mx); sum += v[j]; }
    #pragma unroll
    for (int off = 32; off; off >>= 1) sum += __shfl_xor(sum, off, 64);
    float inv = 1.f / sum;
    short8 o;
    #pragma unroll
    for (int j = 0; j < 8; j++) o[j] = (short)f2us(v[j] * inv);
    *(short8*)&row[lane * 8] = o;
}

__global__ __launch_bounds__(256) void build_citing(
    const bf* __restrict__ x2, const bf* __restrict__ nf,
    const int* __restrict__ citing, bf* __restrict__ cp)
{
    int i = blockIdx.x * 256 + threadIdx.x;
    if (i >= BBATCH * 256) return;
    int b = i >> 8, d = i & 255;
    float v;
    if (d < 128) {
        float s = 0.f;
        for (int l = 0; l < LSEQ; l++)
            s += b2f(x2[((long long)b * LSEQ + l) * 128 + d]);
        v = s * (1.f / (float)LSEQ);
    } else {
        v = b2f(nf[(long long)citing[b] * 128 + (d - 128)]);
    }
    cp[i] = f2b(v);
}

// ---------------------------------------------------------------------------
extern "C" void kernel_launch(void* const* d_in, const int* in_sizes, int n_in,
                              void* d_out, int out_size, void* d_ws, size_t ws_size,
                              hipStream_t stream)
{
    const float* emb  = (const float*)d_in[0];
    const float* f1w  = (const float*)d_in[1];
    const float* f1b  = (const float*)d_in[2];
    const float* g0w1 = (const float*)d_in[3];  const float* g0b1 = (const float*)d_in[4];
    const float* g0w2 = (const float*)d_in[5];  const float* g0b2 = (const float*)d_in[6];
    const float* g1w1 = (const float*)d_in[7];  const float* g1b1 = (const float*)d_in[8];
    const float* g1w2 = (const float*)d_in[9];  const float* g1b2 = (const float*)d_in[10];
    const float* ipw  = (const float*)d_in[11]; const float* ipb  = (const float*)d_in[12];
    const float* opw  = (const float*)d_in[13]; const float* opb  = (const float*)d_in[14];
    const float* ln1s = (const float*)d_in[15]; const float* ln1b = (const float*)d_in[16];
    const float* ff1w = (const float*)d_in[17]; const float* ff1b = (const float*)d_in[18];
    const float* ff2w = (const float*)d_in[19]; const float* ff2b = (const float*)d_in[20];
    const float* ln2s = (const float*)d_in[21]; const float* ln2b = (const float*)d_in[22];
    const float* adj  = (const float*)d_in[23];
    const float* nfe  = (const float*)d_in[24];
    const int* citing = (const int*)d_in[26];
    const int* useqs  = (const int*)d_in[28];
    float* outp = (float*)d_out;

    size_t off = 0;
    auto carve = [&](size_t bytes) -> char* {
        char* p = (char*)d_ws + off;
        off += (bytes + 255) & ~(size_t)255;
        return p;
    };
    bf* adjb = (bf*)carve((size_t)NN * NN * 2);       // bf16 copy of adj (288 MB)
    bf* nf   = (bf*)carve((size_t)NN * DD * 2);
    bf* bufP = (bf*)carve((size_t)NN * DD * 2);
    bf* bufQ = (bf*)carve((size_t)NN * DD * 2);
    bf* BT   = (bf*)carve((size_t)NN * DD * 2);       // transposed [128][12000]
    bf* Hbuf = (bf*)carve((size_t)NN * HIDC * 2);
    float* part = (float*)carve((size_t)AZ * NN * DD * 4);   // 30 MB
    bf* seq  = (bf*)carve((size_t)10240 * DD * 2);
    bf* qkv  = (bf*)carve((size_t)10240 * 384 * 2);
    bf* Sb   = (bf*)carve((size_t)80 * 512 * 512 * 2);
    bf* w10T = (bf*)carve((size_t)DD * HIDC * 2);
    bf* w20T = (bf*)carve((size_t)DD * HIDC * 2);
    bf* w11T = (bf*)carve((size_t)DD * HIDC * 2);
    bf* w21T = (bf*)carve((size_t)DD * HIDC * 2);
    // aliases (regions dead by the time these are live)
    bf* x1ln = (bf*)Hbuf;
    bf* cp   = (bf*)((char*)Hbuf + (size_t)10240 * DD * 2);
    char* pr = (char*)part;
    bf* VT   = (bf*)pr; pr += (size_t)80 * 32 * 512 * 2;
    bf* o_   = (bf*)pr; pr += (size_t)10240 * DD * 2;
    bf* ffh  = (bf*)pr; pr += (size_t)10240 * FFDIM * 2;
    bf* x2   = (bf*)pr; pr += (size_t)10240 * DD * 2;

    dim3 tb(256), tb512(512), tt(32, 8);
    const long long NM = (long long)NN * DD;   // 1,536,000

    // all 4 GCN weight transposes in one dispatch
    transpose4_k<<<dim3(8, 8, 4), tt, 0, stream>>>(
        g0w1, g0w2, g1w1, g1w2, w10T, w20T, w11T, w21T);

    // nf = node_feature @ f1_w^T + f1_b  AND  BT = (emb .* nf)^T  (fused)
    gemm_nf<<<dim3(94), tb, 0, stream>>>(nfe, f1w, f1b, emb, nf, BT);

    const float* biases1[2] = { g0b1, g1b1 };
    const bf* w1T[2] = { w10T, w11T };
    const bf* w2T[2] = { w20T, w21T };

    for (int g = 0; g < 2; g++) {
        // t = A @ x  (x^T in BT), K-split 5
        if (g == 0) {
            gemm128<true, false, false, false, true, true><<<dim3(94, AZ), tb, 0, stream>>>(
                adj, NN, AKS, 0, BT, NN, AKS, 0, nullptr,
                part, DD, NM, 0, NN, DD, AKS, 1, 1, 1.f, adjb);
        } else {
            adj_gemm8<<<dim3(94, AZ), tb512, 0, stream>>>(adjb, BT, part);
        }
        bf* tbuf = (g == 0) ? bufP : bufQ;
        reduceK<<<dim3((NM + 255) / 256), tb, 0, stream>>>(part, nullptr, tbuf, (int)NM, AZ, NM);
        // h = relu(t @ W1 + b1)   [12000,256]
        gemm128<false, false, true, true, false, false><<<dim3(188, 1), tb, 0, stream>>>(
            tbuf, DD, 0, 0, w1T[g], DD, 0, 0, biases1[g],
            Hbuf, HIDC, 0, 0, NN, HIDC, DD, 2, 1, 1.f, nullptr);
        // BT = (h @ W2)^T  directly
        gemm_t2<<<dim3(94), tb, 0, stream>>>(Hbuf, w2T[g], BT);
        // x' = A @ t2 + b2
        adj_gemm8<<<dim3(94, AZ), tb512, 0, stream>>>(adjb, BT, part);
        if (g == 0) {
            reduceKT<<<dim3(375, 4), tt, 0, stream>>>(part, g0b2, BT);
        } else {
            reduceK<<<dim3((NM + 255) / 256), tb, 0, stream>>>(part, g1b2, bufQ, (int)NM, AZ, NM);
        }
    }
    bf* item = bufQ;

    // seq = item[u_seqs]   [10240,128]
    gather_rows<<<dim3(640), tb, 0, stream>>>(item, useqs, seq, 10240);
    // qkv = seq @ in_proj_w^T + b   [10240,384]
    gemm128<false, true, true, false, false, false><<<dim3(240, 1), tb, 0, stream>>>(
        seq, DD, 0, 0, ipw, DD, 0, 0, ipb,
        qkv, 384, 0, 0, 10240, 384, DD, 3, 1, 1.f, nullptr);
    // VT[z=(n,h)][d][t] from qkv V slice
    transpose_k<false><<<dim3(16, 1, 80), tt, 0, stream>>>(
        qkv + 256, 7680, 384, 32, 4, nullptr, 0, VT, 512, 16384, 512, 32);
    // S[z] = alpha * Q_z @ K_z^T   (z = n*4+h), M=N=512, K=32
    gemm128<false, false, false, false, false, false><<<dim3(16, 80), tb, 0, stream>>>(
        qkv, 7680, 384, 32, qkv + 128, 7680, 384, 32, nullptr,
        Sb, 512, (long long)4 * 262144, 262144, 512, 512, 32, 4, 4, 0.17677669529663687f, nullptr);
    // softmax rows (in place)
    softmax512<<<dim3(10240), tb, 0, stream>>>(Sb, 80 * 512);
    // o = P @ V   -> o[s][n][h*32+d]
    gemm128<false, false, false, false, false, false><<<dim3(4, 80), tb, 0, stream>>>(
        Sb, 512, (long long)4 * 262144, 262144, VT, 512, (long long)4 * 16384, 16384, nullptr,
        o_, 2560, 128, 32, 512, 32, 512, 1, 4, 1.f, nullptr);
    // x1 = LN(seq + o @ out_proj^T + b)   (fused GEMM+residual+LN)
    gemm_ln<<<dim3(80), tb, 0, stream>>>(o_, DD, opw, opb, seq, ln1s, ln1b, x1ln, DD);
    // ffh = relu(x1 @ ff1^T + b)   [10240,512]
    gemm128<false, true, true, true, false, false><<<dim3(320, 1), tb, 0, stream>>>(
        x1ln, DD, 0, 0, ff1w, DD, 0, 0, ff1b,
        ffh, FFDIM, 0, 0, 10240, FFDIM, DD, 4, 1, 1.f, nullptr);
    // x2 = LN(x1 + ffh @ ff2^T + b)   (fused GEMM+residual+LN)
    gemm_ln<<<dim3(80), tb, 0, stream>>>(ffh, FFDIM, ff2w, ff2b, x1ln, ln2s, ln2b, x2, FFDIM);
    // citing_paper
    build_citing<<<dim3(512), tb, 0, stream>>>(x2, nf, citing, cp);
    // scores = cp @ [item|nf]^T   [512,12000]  (f32 out, split-B)
    gemm_scores<<<dim3(376), tb, 0, stream>>>(cp, item, nf, outp);
}

// Round 20
// 707.443 us; speedup vs baseline: 1.0403x; 1.0121x over previous
//
#include <hip/hip_runtime.h>
#include <hip/hip_bf16.h>

typedef __hip_bfloat16 bf;
typedef __attribute__((ext_vector_type(4))) float f32x4;
typedef __attribute__((ext_vector_type(8))) __bf16 bf16x8;
typedef __attribute__((ext_vector_type(8))) short short8;
typedef __attribute__((ext_vector_type(4))) short short4v;

#define NN 12000
#define DD 128
#define HIDC 256
#define BBATCH 512
#define LSEQ 20
#define FFEAT 400
#define FFDIM 512
#define AZ 5
#define AKS (NN / AZ)     // 2400 = 37*64 + 32

__device__ __forceinline__ float b2f(bf v) { return __bfloat162float(v); }
__device__ __forceinline__ bf f2b(float v) { return __float2bfloat16(v); }
__device__ __forceinline__ float us2f(unsigned short u) {
    return __uint_as_float(((unsigned int)u) << 16);
}
__device__ __forceinline__ unsigned short f2us(float f) {
    bf h = __float2bfloat16(f);
    return __builtin_bit_cast(unsigned short, h);
}

__device__ __forceinline__ void gload_lds16(const bf* g, bf* l) {
    __builtin_amdgcn_global_load_lds(
        (__attribute__((address_space(1))) void*)(g),
        (__attribute__((address_space(3))) void*)(l),
        16, 0, 0);
}

template<bool F32>
__device__ __forceinline__ short8 ld8(const void* p, long long idx) {
    if (F32) {
        const float* fp = (const float*)p + idx;
        f32x4 u0 = *(const f32x4*)fp;
        f32x4 u1 = *(const f32x4*)(fp + 4);
        short8 s;
        s[0] = (short)f2us(u0[0]); s[1] = (short)f2us(u0[1]);
        s[2] = (short)f2us(u0[2]); s[3] = (short)f2us(u0[3]);
        s[4] = (short)f2us(u1[0]); s[5] = (short)f2us(u1[1]);
        s[6] = (short)f2us(u1[2]); s[7] = (short)f2us(u1[3]);
        return s;
    } else {
        return *(const short8*)((const bf*)p + idx);
    }
}

template<bool F32>
__device__ __forceinline__ bf ldelem(const void* p, long long idx) {
    if (F32) return f2b(((const float*)p)[idx]);
    return ((const bf*)p)[idx];
}

// ---------------------------------------------------------------------------
// adj pass v8 (R13 best): BK=64, 4-buffer ring, prefetch 3, one barrier/step.
// ---------------------------------------------------------------------------
__global__ __launch_bounds__(512) void adj_gemm8(
    const bf* __restrict__ A,    // adjb [NN][NN]
    const bf* __restrict__ Bt,   // BT [128][NN]
    float* __restrict__ part)    // [AZ][NN][128]
{
    alignas(16) __shared__ bf As[4][128 * 64];
    alignas(16) __shared__ bf Bs[4][128 * 64];
    const int tid = threadIdx.x;
    const int lane = tid & 63;
    const int w = tid >> 6;                       // 0..7
    const int z = blockIdx.y;
    const long long k0 = (long long)z * AKS;
    int m0 = blockIdx.x * 128;
    if (m0 > NN - 128) m0 = NN - 128;

    const int rowi = lane >> 3;
    const int chks = (lane & 7) ^ rowi;
    const bf* gA[2]; const bf* gB[2]; int lo[2];
    #pragma unroll
    for (int i = 0; i < 2; i++) {
        int rbase = 16 * w + 8 * i;
        gA[i] = A  + (long long)(m0 + rbase + rowi) * NN + k0 + chks * 8;
        gB[i] = Bt + (long long)(rbase + rowi) * NN + k0 + chks * 8;
        lo[i] = rbase * 64;
    }
    const int rowiT = lane >> 2;
    const int chksT = (lane & 3) ^ ((lane >> 3) & 3);
    const bf* gAT = A  + (long long)(m0 + 16 * w + rowiT) * NN + k0 + 2368 + chksT * 8;
    const bf* gBT = Bt + (long long)(16 * w + rowiT) * NN + k0 + 2368 + chksT * 8;
    const int loT = (16 * w) * 32;

    const int wr = (w >> 1) * 32, wc = (w & 1) * 64;
    const int fr = lane & 15;
    const int kq = lane >> 4;
    int aoff[2][2], boff[2][4], aoffT[2], boffT[4];
    #pragma unroll
    for (int mi = 0; mi < 2; mi++) {
        int ra = wr + mi * 16 + fr;
        aoff[0][mi] = ra * 64 + ((kq)     ^ (ra & 7)) * 8;
        aoff[1][mi] = ra * 64 + ((4 + kq) ^ (ra & 7)) * 8;
        aoffT[mi]   = ra * 32 + (kq ^ ((ra >> 1) & 3)) * 8;
    }
    #pragma unroll
    for (int ni = 0; ni < 4; ni++) {
        int rb = wc + ni * 16 + fr;
        boff[0][ni] = rb * 64 + ((kq)     ^ (rb & 7)) * 8;
        boff[1][ni] = rb * 64 + ((4 + kq) ^ (rb & 7)) * 8;
        boffT[ni]   = rb * 32 + (kq ^ ((rb >> 1) & 3)) * 8;
    }
    f32x4 acc[2][4] = {};

    auto stage64 = [&](int t, int b) {
        const long long go = (long long)t * 64;
        const int bo = b * (128 * 64);
        #pragma unroll
        for (int i = 0; i < 2; i++) {
            gload_lds16(gA[i] + go, &As[0][0] + bo + lo[i]);
            gload_lds16(gB[i] + go, &Bs[0][0] + bo + lo[i]);
        }
    };
    auto stageTail = [&]() {
        gload_lds16(gAT, &As[1][0] + loT);
        gload_lds16(gBT, &Bs[1][0] + loT);
    };
    auto compute64 = [&](int b) {
        const bf* Ab = &As[0][0] + b * (128 * 64);
        const bf* Bb = &Bs[0][0] + b * (128 * 64);
        #pragma unroll
        for (int s = 0; s < 2; s++) {
            bf16x8 af[2], bfr[4];
            #pragma unroll
            for (int mi = 0; mi < 2; mi++) af[mi]  = *(const bf16x8*)(Ab + aoff[s][mi]);
            #pragma unroll
            for (int ni = 0; ni < 4; ni++) bfr[ni] = *(const bf16x8*)(Bb + boff[s][ni]);
            #pragma unroll
            for (int mi = 0; mi < 2; mi++)
                #pragma unroll
                for (int ni = 0; ni < 4; ni++)
                    acc[mi][ni] = __builtin_amdgcn_mfma_f32_16x16x32_bf16(
                        af[mi], bfr[ni], acc[mi][ni], 0, 0, 0);
        }
    };

    stage64(0, 0);
    stage64(1, 1);
    stage64(2, 2);

    #pragma unroll 1
    for (int t = 0; t < 35; t++) {
        asm volatile("s_waitcnt vmcnt(8)" ::: "memory");
        __builtin_amdgcn_s_barrier();
        __builtin_amdgcn_sched_barrier(0);
        compute64(t & 3);
        if (t < 34) stage64(t + 3, (t + 3) & 3);
        else        stageTail();
    }
    asm volatile("s_waitcnt vmcnt(6)" ::: "memory");
    __builtin_amdgcn_s_barrier();
    __builtin_amdgcn_sched_barrier(0);
    compute64(3);
    asm volatile("s_waitcnt vmcnt(2)" ::: "memory");
    __builtin_amdgcn_s_barrier();
    __builtin_amdgcn_sched_barrier(0);
    compute64(0);
    asm volatile("s_waitcnt vmcnt(0)" ::: "memory");
    __builtin_amdgcn_s_barrier();
    __builtin_amdgcn_sched_barrier(0);
    {
        bf16x8 af[2], bfr[4];
        #pragma unroll
        for (int mi = 0; mi < 2; mi++) af[mi]  = *(const bf16x8*)(&As[1][0] + aoffT[mi]);
        #pragma unroll
        for (int ni = 0; ni < 4; ni++) bfr[ni] = *(const bf16x8*)(&Bs[1][0] + boffT[ni]);
        #pragma unroll
        for (int mi = 0; mi < 2; mi++)
            #pragma unroll
            for (int ni = 0; ni < 4; ni++)
                acc[mi][ni] = __builtin_amdgcn_mfma_f32_16x16x32_bf16(
                    af[mi], bfr[ni], acc[mi][ni], 0, 0, 0);
    }

    float* C = part + (long long)z * ((long long)NN * 128);
    const int cr0 = (lane >> 4) * 4;
    const int cc = lane & 15;
    #pragma unroll
    for (int mi = 0; mi < 2; mi++) {
        #pragma unroll
        for (int ni = 0; ni < 4; ni++) {
            int col = wc + ni * 16 + cc;
            #pragma unroll
            for (int j = 0; j < 4; j++) {
                int row = m0 + wr + mi * 16 + cr0 + j;
                C[(long long)row * 128 + col] = acc[mi][ni][j];
            }
        }
    }
}

// ---------------------------------------------------------------------------
// Generic batched MFMA GEMM: C = act(alpha * A @ B^T + bias)
// ---------------------------------------------------------------------------
template<bool A_F32, bool B_F32, bool HAS_BIAS, bool RELU, bool OUT_F32, bool SIDE_A>
__global__ __launch_bounds__(256) void gemm128(
    const void* __restrict__ A, int lda, long long sA1, long long sA2,
    const void* __restrict__ Bm, int ldb, long long sB1, long long sB2,
    const float* __restrict__ bias,
    void* __restrict__ Cv, int ldc, long long sC1, long long sC2,
    int M, int N, int K, int tilesN, int zdiv, float alpha,
    bf* __restrict__ sideA)
{
    __shared__ bf As[128][40];
    __shared__ bf Bs[128][40];
    const int tid = threadIdx.x;
    const int z = blockIdx.y;
    const int zq = z / zdiv, zr = z - zq * zdiv;
    const char* Ap = (const char*)A;
    const char* Bp = (const char*)Bm;
    const long long offA = (long long)zq * sA1 + (long long)zr * sA2;
    const long long offB = (long long)zq * sB1 + (long long)zr * sB2;
    const long long offC = (long long)zq * sC1 + (long long)zr * sC2;
    const int tm = blockIdx.x / tilesN, tn = blockIdx.x - tm * tilesN;
    int m0 = tm * 128; if (m0 > M - 128) m0 = M - 128;
    const int n0 = tn * 128;
    const int lane = tid & 63;
    const int wv = tid >> 6;
    const int wr = (wv >> 1) * 64, wc = (wv & 1) * 64;
    const int fr = lane & 15;
    const int kq = (lane >> 4) * 8;
    const int sr = tid >> 2, scol = (tid & 3) * 8;
    f32x4 acc[4][4] = {};

    for (int k0 = 0; k0 < K; k0 += 32) {
        if (k0 + 32 <= K) {
            const long long ia0 = offA + (long long)(m0 + sr) * lda + k0 + scol;
            const long long ia1 = offA + (long long)(m0 + sr + 64) * lda + k0 + scol;
            short8 va0 = ld8<A_F32>(Ap, ia0);
            short8 va1 = ld8<A_F32>(Ap, ia1);
            short8 vb0 = {0,0,0,0,0,0,0,0}, vb1 = {0,0,0,0,0,0,0,0};
            if (n0 + sr < N)      vb0 = ld8<B_F32>(Bp, offB + (long long)(n0 + sr) * ldb + k0 + scol);
            if (n0 + sr + 64 < N) vb1 = ld8<B_F32>(Bp, offB + (long long)(n0 + sr + 64) * ldb + k0 + scol);
            if (SIDE_A) {
                *(short8*)&sideA[ia0] = va0;
                *(short8*)&sideA[ia1] = va1;
            }
            *(short8*)&As[sr][scol] = va0;
            *(short8*)&As[sr + 64][scol] = va1;
            *(short8*)&Bs[sr][scol] = vb0;
            *(short8*)&Bs[sr + 64][scol] = vb1;
        } else {
            bf zv = f2b(0.f);
            for (int i = tid; i < 128 * 32; i += 256) {
                int r = i >> 5, c = i & 31, gk = k0 + c;
                As[r][c] = (gk < K) ? ldelem<A_F32>(Ap, offA + (long long)(m0 + r) * lda + gk) : zv;
                Bs[r][c] = (gk < K && n0 + r < N) ? ldelem<B_F32>(Bp, offB + (long long)(n0 + r) * ldb + gk) : zv;
            }
        }
        __syncthreads();
        bf16x8 af[4], bfg[4];
        #pragma unroll
        for (int i = 0; i < 4; i++) af[i]  = *(const bf16x8*)&As[wr + i * 16 + fr][kq];
        #pragma unroll
        for (int i = 0; i < 4; i++) bfg[i] = *(const bf16x8*)&Bs[wc + i * 16 + fr][kq];
        #pragma unroll
        for (int mi = 0; mi < 4; mi++)
            #pragma unroll
            for (int ni = 0; ni < 4; ni++)
                acc[mi][ni] = __builtin_amdgcn_mfma_f32_16x16x32_bf16(
                    af[mi], bfg[ni], acc[mi][ni], 0, 0, 0);
        __syncthreads();
    }

    const int cr0 = (lane >> 4) * 4;
    const int cc = lane & 15;
    #pragma unroll
    for (int mi = 0; mi < 4; mi++) {
        #pragma unroll
        for (int ni = 0; ni < 4; ni++) {
            int col = n0 + wc + ni * 16 + cc;
            if (col >= N) continue;
            float bv = 0.f;
            if (HAS_BIAS) bv = bias[col];
            #pragma unroll
            for (int j = 0; j < 4; j++) {
                int row = m0 + wr + mi * 16 + cr0 + j;
                float v = acc[mi][ni][j] * alpha + bv;
                if (RELU) v = fmaxf(v, 0.f);
                if (OUT_F32) ((float*)Cv)[offC + (long long)row * ldc + col] = v;
                else ((bf*)Cv)[offC + (long long)row * ldc + col] = f2b(v);
            }
        }
    }
}

// ---------------------------------------------------------------------------
// h-GEMM with FUSED 5-way partial reduce on the A operand:
// H = relu( (sum_z part[z]) @ w1T^T + b1 ).  BN=256 (full N in one tile) so
// the reduced A tile is staged exactly once. 512 threads, 8 waves (2M x 4N,
// 64x64 out/wave). Replaces reduceK(part->tbuf) + gemm128 h per module.
// ---------------------------------------------------------------------------
__global__ __launch_bounds__(512) void gemm_h(
    const float* __restrict__ part,   // [AZ][NN][128]
    const bf* __restrict__ Bw,        // w1T [256][128]
    const float* __restrict__ bias,   // b1 [256]
    bf* __restrict__ H)               // [NN][256]
{
    __shared__ bf As[128][40];
    __shared__ bf Bs[256][40];
    const int tid = threadIdx.x;
    int m0 = blockIdx.x * 128;
    if (m0 > NN - 128) m0 = NN - 128;   // overlap rows: identical writes
    const int lane = tid & 63;
    const int w = tid >> 6;
    const int wr = (w >> 2) * 64, wc = (w & 3) * 64;
    const int fr = lane & 15;
    const int kq = (lane >> 4) * 8;
    const long long zs = (long long)NN * 128;
    const int sr = tid >> 2, scol = (tid & 3) * 8;        // A: 128 rows x 32 cols
    const int sr2 = tid >> 1, scol2 = (tid & 1) * 16;     // B: 256 rows x 32 cols
    f32x4 acc[4][4] = {};

    for (int k0 = 0; k0 < 128; k0 += 32) {
        // A staging: 5-way f32 reduce -> bf16 (identical math to reduceK, no bias)
        {
            const float* pb = part + (long long)(m0 + sr) * 128 + k0 + scol;
            f32x4 s0 = *(const f32x4*)(pb);
            f32x4 s1 = *(const f32x4*)(pb + 4);
            #pragma unroll
            for (int z = 1; z < AZ; z++) {
                s0 += *(const f32x4*)(pb + (long long)z * zs);
                s1 += *(const f32x4*)(pb + (long long)z * zs + 4);
            }
            short8 v;
            #pragma unroll
            for (int j = 0; j < 4; j++) {
                v[j]     = (short)f2us(s0[j]);
                v[4 + j] = (short)f2us(s1[j]);
            }
            *(short8*)&As[sr][scol] = v;
        }
        // B staging: two short8 per thread
        *(short8*)&Bs[sr2][scol2]     = *(const short8*)(Bw + (long long)sr2 * 128 + k0 + scol2);
        *(short8*)&Bs[sr2][scol2 + 8] = *(const short8*)(Bw + (long long)sr2 * 128 + k0 + scol2 + 8);
        __syncthreads();
        bf16x8 af[4], bfg[4];
        #pragma unroll
        for (int i = 0; i < 4; i++) af[i]  = *(const bf16x8*)&As[wr + i * 16 + fr][kq];
        #pragma unroll
        for (int i = 0; i < 4; i++) bfg[i] = *(const bf16x8*)&Bs[wc + i * 16 + fr][kq];
        #pragma unroll
        for (int mi = 0; mi < 4; mi++)
            #pragma unroll
            for (int ni = 0; ni < 4; ni++)
                acc[mi][ni] = __builtin_amdgcn_mfma_f32_16x16x32_bf16(
                    af[mi], bfg[ni], acc[mi][ni], 0, 0, 0);
        __syncthreads();
    }

    const int cr0 = (lane >> 4) * 4;
    const int cc = lane & 15;
    #pragma unroll
    for (int mi = 0; mi < 4; mi++) {
        #pragma unroll
        for (int ni = 0; ni < 4; ni++) {
            int col = wc + ni * 16 + cc;
            float bv = bias[col];
            #pragma unroll
            for (int j = 0; j < 4; j++) {
                int row = m0 + wr + mi * 16 + cr0 + j;
                H[(long long)row * 256 + col] = f2b(fmaxf(acc[mi][ni][j] + bv, 0.f));
            }
        }
    }
}

// ---------------------------------------------------------------------------
// nf GEMM with fused BT write (R19-verified).
// ---------------------------------------------------------------------------
__global__ __launch_bounds__(256) void gemm_nf(
    const float* __restrict__ A,     // node_feature [NN][400]
    const float* __restrict__ Bw,    // f1w [128][400]
    const float* __restrict__ bias,  // f1b [128]
    const float* __restrict__ emb,   // [NN][128] f32
    bf* __restrict__ nfp,            // [NN][128]
    bf* __restrict__ BT)             // [128][NN]
{
    __shared__ bf As[128][40];
    __shared__ bf Bs[128][40];
    const int tid = threadIdx.x;
    int m0 = blockIdx.x * 128;
    if (m0 > NN - 128) m0 = NN - 128;
    const int lane = tid & 63;
    const int wv = tid >> 6;
    const int wr = (wv >> 1) * 64, wc = (wv & 1) * 64;
    const int fr = lane & 15;
    const int kq = (lane >> 4) * 8;
    const int sr = tid >> 2, scol = (tid & 3) * 8;
    f32x4 acc[4][4] = {};

    for (int k0 = 0; k0 < FFEAT; k0 += 32) {
        if (k0 + 32 <= FFEAT) {
            *(short8*)&As[sr][scol]      = ld8<true>(A, (long long)(m0 + sr) * FFEAT + k0 + scol);
            *(short8*)&As[sr + 64][scol] = ld8<true>(A, (long long)(m0 + sr + 64) * FFEAT + k0 + scol);
            *(short8*)&Bs[sr][scol]      = ld8<true>(Bw, (long long)sr * FFEAT + k0 + scol);
            *(short8*)&Bs[sr + 64][scol] = ld8<true>(Bw, (long long)(sr + 64) * FFEAT + k0 + scol);
        } else {
            bf zv = f2b(0.f);
            for (int i = tid; i < 128 * 32; i += 256) {
                int r = i >> 5, c = i & 31, gk = k0 + c;
                As[r][c] = (gk < FFEAT) ? f2b(A[(long long)(m0 + r) * FFEAT + gk]) : zv;
                Bs[r][c] = (gk < FFEAT) ? f2b(Bw[(long long)r * FFEAT + gk]) : zv;
            }
        }
        __syncthreads();
        bf16x8 af[4], bfg[4];
        #pragma unroll
        for (int i = 0; i < 4; i++) af[i]  = *(const bf16x8*)&As[wr + i * 16 + fr][kq];
        #pragma unroll
        for (int i = 0; i < 4; i++) bfg[i] = *(const bf16x8*)&Bs[wc + i * 16 + fr][kq];
        #pragma unroll
        for (int mi = 0; mi < 4; mi++)
            #pragma unroll
            for (int ni = 0; ni < 4; ni++)
                acc[mi][ni] = __builtin_amdgcn_mfma_f32_16x16x32_bf16(
                    af[mi], bfg[ni], acc[mi][ni], 0, 0, 0);
        __syncthreads();
    }

    const int cr0 = (lane >> 4) * 4;
    const int cc = lane & 15;
    #pragma unroll
    for (int mi = 0; mi < 4; mi++) {
        #pragma unroll
        for (int ni = 0; ni < 4; ni++) {
            int col = wc + ni * 16 + cc;
            int rowb = m0 + wr + mi * 16 + cr0;
            float bv = bias[col];
            short4v tv;
            #pragma unroll
            for (int j = 0; j < 4; j++) {
                bf nv = f2b(acc[mi][ni][j] + bv);
                nfp[(long long)(rowb + j) * 128 + col] = nv;
                tv[j] = (short)f2us(b2f(nv) * emb[(long long)(rowb + j) * 128 + col]);
            }
            *(short4v*)&BT[(long long)col * NN + rowb] = tv;
        }
    }
}

// ---------------------------------------------------------------------------
// t2 GEMM with TRANSPOSED output (R16-verified).
// ---------------------------------------------------------------------------
__global__ __launch_bounds__(256) void gemm_t2(
    const bf* __restrict__ A,
    const bf* __restrict__ Bw,
    bf* __restrict__ BT)
{
    __shared__ bf As[128][40];
    __shared__ bf Bs[128][40];
    const int tid = threadIdx.x;
    int m0 = blockIdx.x * 128;
    if (m0 > NN - 128) m0 = NN - 128;
    const int lane = tid & 63;
    const int wv = tid >> 6;
    const int wr = (wv >> 1) * 64, wc = (wv & 1) * 64;
    const int fr = lane & 15;
    const int kq = (lane >> 4) * 8;
    const int sr = tid >> 2, scol = (tid & 3) * 8;
    f32x4 acc[4][4] = {};

    for (int k0 = 0; k0 < 256; k0 += 32) {
        *(short8*)&As[sr][scol]      = ld8<false>(A, (long long)(m0 + sr) * 256 + k0 + scol);
        *(short8*)&As[sr + 64][scol] = ld8<false>(A, (long long)(m0 + sr + 64) * 256 + k0 + scol);
        *(short8*)&Bs[sr][scol]      = ld8<false>(Bw, (long long)sr * 256 + k0 + scol);
        *(short8*)&Bs[sr + 64][scol] = ld8<false>(Bw, (long long)(sr + 64) * 256 + k0 + scol);
        __syncthreads();
        bf16x8 af[4], bfg[4];
        #pragma unroll
        for (int i = 0; i < 4; i++) af[i]  = *(const bf16x8*)&As[wr + i * 16 + fr][kq];
        #pragma unroll
        for (int i = 0; i < 4; i++) bfg[i] = *(const bf16x8*)&Bs[wc + i * 16 + fr][kq];
        #pragma unroll
        for (int mi = 0; mi < 4; mi++)
            #pragma unroll
            for (int ni = 0; ni < 4; ni++)
                acc[mi][ni] = __builtin_amdgcn_mfma_f32_16x16x32_bf16(
                    af[mi], bfg[ni], acc[mi][ni], 0, 0, 0);
        __syncthreads();
    }

    const int cr0 = (lane >> 4) * 4;
    const int cc = lane & 15;
    #pragma unroll
    for (int mi = 0; mi < 4; mi++) {
        #pragma unroll
        for (int ni = 0; ni < 4; ni++) {
            int col = wc + ni * 16 + cc;
            int rowb = m0 + wr + mi * 16 + cr0;
            short4v v;
            #pragma unroll
            for (int j = 0; j < 4; j++) v[j] = (short)f2us(acc[mi][ni][j]);
            *(short4v*)&BT[(long long)col * NN + rowb] = v;
        }
    }
}

// ---------------------------------------------------------------------------
// 5-way partial reduce + bias with transposed output (R16-verified).
// ---------------------------------------------------------------------------
__global__ __launch_bounds__(256) void reduceKT(
    const float* __restrict__ part, const float* __restrict__ bias,
    bf* __restrict__ BT)
{
    __shared__ bf t[32][33];
    const long long zs = (long long)NN * 128;
    int r0 = blockIdx.x * 32, c0 = blockIdx.y * 32;
    int tx = threadIdx.x, ty = threadIdx.y;   // 32 x 8
    #pragma unroll
    for (int i = 0; i < 4; i++) {
        int r = r0 + ty + i * 8, c = c0 + tx;
        float s = bias[c];
        #pragma unroll
        for (int z = 0; z < AZ; z++) s += part[(long long)z * zs + (long long)r * 128 + c];
        t[ty + i * 8][tx] = f2b(s);
    }
    __syncthreads();
    #pragma unroll
    for (int i = 0; i < 4; i++) {
        int c = c0 + ty + i * 8, r = r0 + tx;
        BT[(long long)c * NN + r] = t[tx][ty + i * 8];
    }
}

// ---------------------------------------------------------------------------
// GEMM with fused residual + LayerNorm epilogue (R15-verified).
// ---------------------------------------------------------------------------
__global__ __launch_bounds__(256) void gemm_ln(
    const bf* __restrict__ A, int lda,
    const float* __restrict__ Bw,
    const float* __restrict__ bias,
    const bf* __restrict__ resid,
    const float* __restrict__ lnS, const float* __restrict__ lnB,
    bf* __restrict__ outp, int K)
{
    __shared__ bf As[128][40];
    __shared__ bf Bs[128][40];
    __shared__ float red[128][2][2];
    const int tid = threadIdx.x;
    const int m0 = blockIdx.x * 128;
    const int lane = tid & 63;
    const int wv = tid >> 6;
    const int wr = (wv >> 1) * 64, wc = (wv & 1) * 64;
    const int fr = lane & 15;
    const int kq = (lane >> 4) * 8;
    const int sr = tid >> 2, scol = (tid & 3) * 8;
    f32x4 acc[4][4] = {};

    for (int k0 = 0; k0 < K; k0 += 32) {
        short8 va0 = ld8<false>(A, (long long)(m0 + sr) * lda + k0 + scol);
        short8 va1 = ld8<false>(A, (long long)(m0 + sr + 64) * lda + k0 + scol);
        short8 vb0 = ld8<true>(Bw, (long long)sr * K + k0 + scol);
        short8 vb1 = ld8<true>(Bw, (long long)(sr + 64) * K + k0 + scol);
        *(short8*)&As[sr][scol] = va0;
        *(short8*)&As[sr + 64][scol] = va1;
        *(short8*)&Bs[sr][scol] = vb0;
        *(short8*)&Bs[sr + 64][scol] = vb1;
        __syncthreads();
        bf16x8 af[4], bfg[4];
        #pragma unroll
        for (int i = 0; i < 4; i++) af[i]  = *(const bf16x8*)&As[wr + i * 16 + fr][kq];
        #pragma unroll
        for (int i = 0; i < 4; i++) bfg[i] = *(const bf16x8*)&Bs[wc + i * 16 + fr][kq];
        #pragma unroll
        for (int mi = 0; mi < 4; mi++)
            #pragma unroll
            for (int ni = 0; ni < 4; ni++)
                acc[mi][ni] = __builtin_amdgcn_mfma_f32_16x16x32_bf16(
                    af[mi], bfg[ni], acc[mi][ni], 0, 0, 0);
        __syncthreads();
    }

    const int cr0 = (lane >> 4) * 4;
    const int cc = lane & 15;
    #pragma unroll
    for (int mi = 0; mi < 4; mi++)
        #pragma unroll
        for (int ni = 0; ni < 4; ni++) {
            int col = wc + ni * 16 + cc;
            #pragma unroll
            for (int j = 0; j < 4; j++) {
                int row = m0 + wr + mi * 16 + cr0 + j;
                acc[mi][ni][j] += bias[col] + b2f(resid[(long long)row * 128 + col]);
            }
        }
    float s1[4][4], s2[4][4];
    #pragma unroll
    for (int mi = 0; mi < 4; mi++)
        #pragma unroll
        for (int j = 0; j < 4; j++) {
            float a = 0.f, b = 0.f;
            #pragma unroll
            for (int ni = 0; ni < 4; ni++) {
                float x = acc[mi][ni][j];
                a += x; b += x * x;
            }
            #pragma unroll
            for (int off = 1; off < 16; off <<= 1) {
                a += __shfl_xor(a, off, 64);
                b += __shfl_xor(b, off, 64);
            }
            s1[mi][j] = a; s2[mi][j] = b;
        }
    if (cc == 0) {
        #pragma unroll
        for (int mi = 0; mi < 4; mi++)
            #pragma unroll
            for (int j = 0; j < 4; j++) {
                int lr = wr + mi * 16 + cr0 + j;
                red[lr][wv & 1][0] = s1[mi][j];
                red[lr][wv & 1][1] = s2[mi][j];
            }
    }
    __syncthreads();
    #pragma unroll
    for (int mi = 0; mi < 4; mi++)
        #pragma unroll
        for (int ni = 0; ni < 4; ni++) {
            int col = wc + ni * 16 + cc;
            float ls = lnS[col], lb = lnB[col];
            #pragma unroll
            for (int j = 0; j < 4; j++) {
                int lr = wr + mi * 16 + cr0 + j;
                float tot  = red[lr][0][0] + red[lr][1][0];
                float tot2 = red[lr][0][1] + red[lr][1][1];
                float mean = tot * (1.f / 128.f);
                float var  = tot2 * (1.f / 128.f) - mean * mean;
                float inv  = rsqrtf(var + 1e-5f);
                outp[(long long)(m0 + lr) * 128 + col] =
                    f2b((acc[mi][ni][j] - mean) * inv * ls + lb);
            }
        }
}

// ---------------------------------------------------------------------------
// scores GEMM with split B source (R15-verified).
// ---------------------------------------------------------------------------
__global__ __launch_bounds__(256) void gemm_scores(
    const bf* __restrict__ A,    // cp [512][256]
    const bf* __restrict__ B1,   // item [NN][128]
    const bf* __restrict__ B2,   // nf   [NN][128]
    float* __restrict__ outp)    // [512][NN]
{
    __shared__ bf As[128][40];
    __shared__ bf Bs[128][40];
    const int tid = threadIdx.x;
    const int tm = blockIdx.x / 94, tn = blockIdx.x - tm * 94;
    const int m0 = tm * 128;
    const int n0 = tn * 128;
    const int lane = tid & 63;
    const int wv = tid >> 6;
    const int wr = (wv >> 1) * 64, wc = (wv & 1) * 64;
    const int fr = lane & 15;
    const int kq = (lane >> 4) * 8;
    const int sr = tid >> 2, scol = (tid & 3) * 8;
    f32x4 acc[4][4] = {};

    for (int k0 = 0; k0 < 256; k0 += 32) {
        short8 va0 = ld8<false>(A, (long long)(m0 + sr) * 256 + k0 + scol);
        short8 va1 = ld8<false>(A, (long long)(m0 + sr + 64) * 256 + k0 + scol);
        const int gk = k0 + scol;
        const bf* bb = (gk < 128) ? B1 : B2;
        const int kk = gk & 127;
        short8 vb0 = {0,0,0,0,0,0,0,0}, vb1 = {0,0,0,0,0,0,0,0};
        if (n0 + sr < NN)      vb0 = *(const short8*)(bb + (long long)(n0 + sr) * 128 + kk);
        if (n0 + sr + 64 < NN) vb1 = *(const short8*)(bb + (long long)(n0 + sr + 64) * 128 + kk);
        *(short8*)&As[sr][scol] = va0;
        *(short8*)&As[sr + 64][scol] = va1;
        *(short8*)&Bs[sr][scol] = vb0;
        *(short8*)&Bs[sr + 64][scol] = vb1;
        __syncthreads();
        bf16x8 af[4], bfg[4];
        #pragma unroll
        for (int i = 0; i < 4; i++) af[i]  = *(const bf16x8*)&As[wr + i * 16 + fr][kq];
        #pragma unroll
        for (int i = 0; i < 4; i++) bfg[i] = *(const bf16x8*)&Bs[wc + i * 16 + fr][kq];
        #pragma unroll
        for (int mi = 0; mi < 4; mi++)
            #pragma unroll
            for (int ni = 0; ni < 4; ni++)
                acc[mi][ni] = __builtin_amdgcn_mfma_f32_16x16x32_bf16(
                    af[mi], bfg[ni], acc[mi][ni], 0, 0, 0);
        __syncthreads();
    }

    const int cr0 = (lane >> 4) * 4;
    const int cc = lane & 15;
    #pragma unroll
    for (int mi = 0; mi < 4; mi++) {
        #pragma unroll
        for (int ni = 0; ni < 4; ni++) {
            int col = n0 + wc + ni * 16 + cc;
            if (col >= NN) continue;
            #pragma unroll
            for (int j = 0; j < 4; j++) {
                int row = m0 + wr + mi * 16 + cr0 + j;
                outp[(long long)row * NN + col] = acc[mi][ni][j];
            }
        }
    }
}

// all 4 GCN weight transposes in one dispatch
__global__ __launch_bounds__(256) void transpose4_k(
    const float* s0, const float* s1, const float* s2, const float* s3,
    bf* d0, bf* d1, bf* d2, bf* d3)
{
    __shared__ bf t[32][33];
    const int z = blockIdx.z;
    const float* in = (z == 0) ? s0 : (z == 1) ? s1 : (z == 2) ? s2 : s3;
    bf* out = (z == 0) ? d0 : (z == 1) ? d1 : (z == 2) ? d2 : d3;
    const int R = (z & 1) ? HIDC : DD;
    const int C = (z & 1) ? DD : HIDC;
    int r0 = blockIdx.x * 32, c0 = blockIdx.y * 32;
    if (r0 >= R || c0 >= C) return;
    int tx = threadIdx.x, ty = threadIdx.y;   // 32 x 8
    #pragma unroll
    for (int i = 0; i < 4; i++) {
        int r = r0 + ty + i * 8, c = c0 + tx;
        bf v = f2b(0.f);
        if (r < R && c < C) v = f2b(in[(long long)r * C + c]);
        t[ty + i * 8][tx] = v;
    }
    __syncthreads();
    #pragma unroll
    for (int i = 0; i < 4; i++) {
        int c = c0 + ty + i * 8, r = r0 + tx;
        if (c < C && r < R) out[(long long)c * R + r] = t[tx][ty + i * 8];
    }
}

template<bool IN_F32>
__global__ __launch_bounds__(256) void transpose_k(
    const void* __restrict__ in, int ldin, long long sI1, long long sI2, int zdiv,
    const float* __restrict__ mulp, int ldmul,
    bf* __restrict__ outp, int ldout, long long sOut,
    int R, int C)
{
    __shared__ bf t[32][33];
    const int z = blockIdx.z;
    const int zq = z / zdiv, zr = z - zq * zdiv;
    const long long offI = (long long)zq * sI1 + (long long)zr * sI2;
    bf* op = outp + (long long)z * sOut;
    int r0 = blockIdx.x * 32, c0 = blockIdx.y * 32;
    int tx = threadIdx.x, ty = threadIdx.y;   // 32 x 8
    #pragma unroll
    for (int i = 0; i < 4; i++) {
        int r = r0 + ty + i * 8, c = c0 + tx;
        bf v = f2b(0.f);
        if (r < R && c < C) {
            v = ldelem<IN_F32>(in, offI + (long long)r * ldin + c);
            if (mulp) v = f2b(b2f(v) * mulp[(long long)r * ldmul + c]);
        }
        t[ty + i * 8][tx] = v;
    }
    __syncthreads();
    #pragma unroll
    for (int i = 0; i < 4; i++) {
        int c = c0 + ty + i * 8, r = r0 + tx;
        if (c < C && r < R) op[(long long)c * ldout + r] = t[tx][ty + i * 8];
    }
}

__global__ __launch_bounds__(256) void reduceK(
    const float* __restrict__ part, const float* __restrict__ bias,
    bf* __restrict__ outp, int total, int nz, long long zs)
{
    int i = blockIdx.x * 256 + threadIdx.x;
    if (i >= total) return;
    float s = 0.f;
    for (int zz = 0; zz < nz; zz++) s += part[(long long)zz * zs + i];
    if (bias) s += bias[i & 127];
    outp[i] = f2b(s);
}

__global__ __launch_bounds__(256) void gather_rows(
    const bf* __restrict__ src, const int* __restrict__ idx,
    bf* __restrict__ dst, int nrows)
{
    int t = blockIdx.x * 256 + threadIdx.x;
    int row = t >> 4, p = t & 15;
    if (row >= nrows) return;
    long long srow = idx[row];
    *(short8*)&dst[(long long)row * 128 + p * 8] =
        *(const short8*)&src[srow * 128 + p * 8];
}

__global__ __launch_bounds__(256) void softmax512(bf* __restrict__ S, int nrows)
{
    int gid = blockIdx.x * 256 + threadIdx.x;
    int wid = gid >> 6, lane = gid & 63;
    if (wid >= nrows) return;
    bf* row = S + (long long)wid * 512;
    short8 raw = *(const short8*)&row[lane * 8];
    float v[8];
    float mx = -3.0e38f;
    #pragma unroll
    for (int j = 0; j < 8; j++) {
        v[j] = us2f((unsigned short)raw[j]);
        mx = fmaxf(mx, v[j]);
    }
    #pragma unroll
    for (int off = 32; off; off >>= 1) mx = fmaxf(mx, __shfl_xor(mx, off, 64));
    float sum = 0.f;
    #pragma unroll
    for (int j = 0; j < 8; j++) { v[j] = __expf(v[j] - mx); sum += v[j]; }
    #pragma unroll
    for (int off = 32; off; off >>= 1) sum += __shfl_xor(sum, off, 64);
    float inv = 1.f / sum;
    short8 o;
    #pragma unroll
    for (int j = 0; j < 8; j++) o[j] = (short)f2us(v[j] * inv);
    *(short8*)&row[lane * 8] = o;
}

__global__ __launch_bounds__(256) void build_citing(
    const bf* __restrict__ x2, const bf* __restrict__ nf,
    const int* __restrict__ citing, bf* __restrict__ cp)
{
    int i = blockIdx.x * 256 + threadIdx.x;
    if (i >= BBATCH * 256) return;
    int b = i >> 8, d = i & 255;
    float v;
    if (d < 128) {
        float s = 0.f;
        for (int l = 0; l < LSEQ; l++)
            s += b2f(x2[((long long)b * LSEQ + l) * 128 + d]);
        v = s * (1.f / (float)LSEQ);
    } else {
        v = b2f(nf[(long long)citing[b] * 128 + (d - 128)]);
    }
    cp[i] = f2b(v);
}

// ---------------------------------------------------------------------------
extern "C" void kernel_launch(void* const* d_in, const int* in_sizes, int n_in,
                              void* d_out, int out_size, void* d_ws, size_t ws_size,
                              hipStream_t stream)
{
    const float* emb  = (const float*)d_in[0];
    const float* f1w  = (const float*)d_in[1];
    const float* f1b  = (const float*)d_in[2];
    const float* g0w1 = (const float*)d_in[3];  const float* g0b1 = (const float*)d_in[4];
    const float* g0w2 = (const float*)d_in[5];  const float* g0b2 = (const float*)d_in[6];
    const float* g1w1 = (const float*)d_in[7];  const float* g1b1 = (const float*)d_in[8];
    const float* g1w2 = (const float*)d_in[9];  const float* g1b2 = (const float*)d_in[10];
    const float* ipw  = (const float*)d_in[11]; const float* ipb  = (const float*)d_in[12];
    const float* opw  = (const float*)d_in[13]; const float* opb  = (const float*)d_in[14];
    const float* ln1s = (const float*)d_in[15]; const float* ln1b = (const float*)d_in[16];
    const float* ff1w = (const float*)d_in[17]; const float* ff1b = (const float*)d_in[18];
    const float* ff2w = (const float*)d_in[19]; const float* ff2b = (const float*)d_in[20];
    const float* ln2s = (const float*)d_in[21]; const float* ln2b = (const float*)d_in[22];
    const float* adj  = (const float*)d_in[23];
    const float* nfe  = (const float*)d_in[24];
    const int* citing = (const int*)d_in[26];
    const int* useqs  = (const int*)d_in[28];
    float* outp = (float*)d_out;

    size_t off = 0;
    auto carve = [&](size_t bytes) -> char* {
        char* p = (char*)d_ws + off;
        off += (bytes + 255) & ~(size_t)255;
        return p;
    };
    bf* adjb = (bf*)carve((size_t)NN * NN * 2);       // bf16 copy of adj (288 MB)
    bf* nf   = (bf*)carve((size_t)NN * DD * 2);
    bf* bufP = (bf*)carve((size_t)NN * DD * 2);
    bf* bufQ = (bf*)carve((size_t)NN * DD * 2);
    bf* BT   = (bf*)carve((size_t)NN * DD * 2);       // transposed [128][12000]
    bf* Hbuf = (bf*)carve((size_t)NN * HIDC * 2);
    float* part = (float*)carve((size_t)AZ * NN * DD * 4);   // 30 MB
    bf* seq  = (bf*)carve((size_t)10240 * DD * 2);
    bf* qkv  = (bf*)carve((size_t)10240 * 384 * 2);
    bf* Sb   = (bf*)carve((size_t)80 * 512 * 512 * 2);
    bf* w10T = (bf*)carve((size_t)DD * HIDC * 2);
    bf* w20T = (bf*)carve((size_t)DD * HIDC * 2);
    bf* w11T = (bf*)carve((size_t)DD * HIDC * 2);
    bf* w21T = (bf*)carve((size_t)DD * HIDC * 2);
    // aliases (regions dead by the time these are live)
    bf* x1ln = (bf*)Hbuf;
    bf* cp   = (bf*)((char*)Hbuf + (size_t)10240 * DD * 2);
    char* pr = (char*)part;
    bf* VT   = (bf*)pr; pr += (size_t)80 * 32 * 512 * 2;
    bf* o_   = (bf*)pr; pr += (size_t)10240 * DD * 2;
    bf* ffh  = (bf*)pr; pr += (size_t)10240 * FFDIM * 2;
    bf* x2   = (bf*)pr; pr += (size_t)10240 * DD * 2;

    dim3 tb(256), tb512(512), tt(32, 8);
    const long long NM = (long long)NN * DD;   // 1,536,000

    // all 4 GCN weight transposes in one dispatch
    transpose4_k<<<dim3(8, 8, 4), tt, 0, stream>>>(
        g0w1, g0w2, g1w1, g1w2, w10T, w20T, w11T, w21T);

    // nf = node_feature @ f1_w^T + f1_b  AND  BT = (emb .* nf)^T  (fused)
    gemm_nf<<<dim3(94), tb, 0, stream>>>(nfe, f1w, f1b, emb, nf, BT);

    const float* biases1[2] = { g0b1, g1b1 };
    const bf* w1T[2] = { w10T, w11T };
    const bf* w2T[2] = { w20T, w21T };

    for (int g = 0; g < 2; g++) {
        // t = A @ x  (x^T in BT), K-split 5
        if (g == 0) {
            gemm128<true, false, false, false, true, true><<<dim3(94, AZ), tb, 0, stream>>>(
                adj, NN, AKS, 0, BT, NN, AKS, 0, nullptr,
                part, DD, NM, 0, NN, DD, AKS, 1, 1, 1.f, adjb);
        } else {
            adj_gemm8<<<dim3(94, AZ), tb512, 0, stream>>>(adjb, BT, part);
        }
        // h = relu((sum_z part) @ W1 + b1)  (fused reduce + GEMM, BN=256)
        gemm_h<<<dim3(94), tb512, 0, stream>>>(part, w1T[g], biases1[g], Hbuf);
        // BT = (h @ W2)^T  directly
        gemm_t2<<<dim3(94), tb, 0, stream>>>(Hbuf, w2T[g], BT);
        // x' = A @ t2 + b2
        adj_gemm8<<<dim3(94, AZ), tb512, 0, stream>>>(adjb, BT, part);
        if (g == 0) {
            reduceKT<<<dim3(375, 4), tt, 0, stream>>>(part, g0b2, BT);
        } else {
            reduceK<<<dim3((NM + 255) / 256), tb, 0, stream>>>(part, g1b2, bufQ, (int)NM, AZ, NM);
        }
    }
    bf* item = bufQ;

    // seq = item[u_seqs]   [10240,128]
    gather_rows<<<dim3(640), tb, 0, stream>>>(item, useqs, seq, 10240);
    // qkv = seq @ in_proj_w^T + b   [10240,384]
    gemm128<false, true, true, false, false, false><<<dim3(240, 1), tb, 0, stream>>>(
        seq, DD, 0, 0, ipw, DD, 0, 0, ipb,
        qkv, 384, 0, 0, 10240, 384, DD, 3, 1, 1.f, nullptr);
    // VT[z=(n,h)][d][t] from qkv V slice
    transpose_k<false><<<dim3(16, 1, 80), tt, 0, stream>>>(
        qkv + 256, 7680, 384, 32, 4, nullptr, 0, VT, 512, 16384, 512, 32);
    // S[z] = alpha * Q_z @ K_z^T   (z = n*4+h), M=N=512, K=32
    gemm128<false, false, false, false, false, false><<<dim3(16, 80), tb, 0, stream>>>(
        qkv, 7680, 384, 32, qkv + 128, 7680, 384, 32, nullptr,
        Sb, 512, (long long)4 * 262144, 262144, 512, 512, 32, 4, 4, 0.17677669529663687f, nullptr);
    // softmax rows (in place)
    softmax512<<<dim3(10240), tb, 0, stream>>>(Sb, 80 * 512);
    // o = P @ V   -> o[s][n][h*32+d]
    gemm128<false, false, false, false, false, false><<<dim3(4, 80), tb, 0, stream>>>(
        Sb, 512, (long long)4 * 262144, 262144, VT, 512, (long long)4 * 16384, 16384, nullptr,
        o_, 2560, 128, 32, 512, 32, 512, 1, 4, 1.f, nullptr);
    // x1 = LN(seq + o @ out_proj^T + b)   (fused GEMM+residual+LN)
    gemm_ln<<<dim3(80), tb, 0, stream>>>(o_, DD, opw, opb, seq, ln1s, ln1b, x1ln, DD);
    // ffh = relu(x1 @ ff1^T + b)   [10240,512]
    gemm128<false, true, true, true, false, false><<<dim3(320, 1), tb, 0, stream>>>(
        x1ln, DD, 0, 0, ff1w, DD, 0, 0, ff1b,
        ffh, FFDIM, 0, 0, 10240, FFDIM, DD, 4, 1, 1.f, nullptr);
    // x2 = LN(x1 + ffh @ ff2^T + b)   (fused GEMM+residual+LN)
    gemm_ln<<<dim3(80), tb, 0, stream>>>(ffh, FFDIM, ff2w, ff2b, x1ln, ln2s, ln2b, x2, FFDIM);
    // citing_paper
    build_citing<<<dim3(512), tb, 0, stream>>>(x2, nf, citing, cp);
    // scores = cp @ [item|nf]^T   [512,12000]  (f32 out, split-B)
    gemm_scores<<<dim3(376), tb, 0, stream>>>(cp, item, nf, outp);
}

// Round 21
// 705.405 us; speedup vs baseline: 1.0433x; 1.0029x over previous
//
#include <hip/hip_runtime.h>
#include <hip/hip_bf16.h>

typedef __hip_bfloat16 bf;
typedef __attribute__((ext_vector_type(4))) float f32x4;
typedef __attribute__((ext_vector_type(8))) __bf16 bf16x8;
typedef __attribute__((ext_vector_type(8))) short short8;
typedef __attribute__((ext_vector_type(4))) short short4v;

#define NN 12000
#define DD 128
#define HIDC 256
#define BBATCH 512
#define LSEQ 20
#define FFEAT 400
#define FFDIM 512
#define AZ 5
#define AKS (NN / AZ)     // 2400 = 37*64 + 32

__device__ __forceinline__ float b2f(bf v) { return __bfloat162float(v); }
__device__ __forceinline__ bf f2b(float v) { return __float2bfloat16(v); }
__device__ __forceinline__ float us2f(unsigned short u) {
    return __uint_as_float(((unsigned int)u) << 16);
}
__device__ __forceinline__ unsigned short f2us(float f) {
    bf h = __float2bfloat16(f);
    return __builtin_bit_cast(unsigned short, h);
}

__device__ __forceinline__ void gload_lds16(const bf* g, bf* l) {
    __builtin_amdgcn_global_load_lds(
        (__attribute__((address_space(1))) void*)(g),
        (__attribute__((address_space(3))) void*)(l),
        16, 0, 0);
}

template<bool F32>
__device__ __forceinline__ short8 ld8(const void* p, long long idx) {
    if (F32) {
        const float* fp = (const float*)p + idx;
        f32x4 u0 = *(const f32x4*)fp;
        f32x4 u1 = *(const f32x4*)(fp + 4);
        short8 s;
        s[0] = (short)f2us(u0[0]); s[1] = (short)f2us(u0[1]);
        s[2] = (short)f2us(u0[2]); s[3] = (short)f2us(u0[3]);
        s[4] = (short)f2us(u1[0]); s[5] = (short)f2us(u1[1]);
        s[6] = (short)f2us(u1[2]); s[7] = (short)f2us(u1[3]);
        return s;
    } else {
        return *(const short8*)((const bf*)p + idx);
    }
}

template<bool F32>
__device__ __forceinline__ bf ldelem(const void* p, long long idx) {
    if (F32) return f2b(((const float*)p)[idx]);
    return ((const bf*)p)[idx];
}

// ---------------------------------------------------------------------------
// adj pass v8 (R13 best): BK=64, 4-buffer ring, prefetch 3, one barrier/step.
// ---------------------------------------------------------------------------
__global__ __launch_bounds__(512) void adj_gemm8(
    const bf* __restrict__ A,    // adjb [NN][NN]
    const bf* __restrict__ Bt,   // BT [128][NN]
    float* __restrict__ part)    // [AZ][NN][128]
{
    alignas(16) __shared__ bf As[4][128 * 64];
    alignas(16) __shared__ bf Bs[4][128 * 64];
    const int tid = threadIdx.x;
    const int lane = tid & 63;
    const int w = tid >> 6;                       // 0..7
    const int z = blockIdx.y;
    const long long k0 = (long long)z * AKS;
    int m0 = blockIdx.x * 128;
    if (m0 > NN - 128) m0 = NN - 128;

    const int rowi = lane >> 3;
    const int chks = (lane & 7) ^ rowi;
    const bf* gA[2]; const bf* gB[2]; int lo[2];
    #pragma unroll
    for (int i = 0; i < 2; i++) {
        int rbase = 16 * w + 8 * i;
        gA[i] = A  + (long long)(m0 + rbase + rowi) * NN + k0 + chks * 8;
        gB[i] = Bt + (long long)(rbase + rowi) * NN + k0 + chks * 8;
        lo[i] = rbase * 64;
    }
    const int rowiT = lane >> 2;
    const int chksT = (lane & 3) ^ ((lane >> 3) & 3);
    const bf* gAT = A  + (long long)(m0 + 16 * w + rowiT) * NN + k0 + 2368 + chksT * 8;
    const bf* gBT = Bt + (long long)(16 * w + rowiT) * NN + k0 + 2368 + chksT * 8;
    const int loT = (16 * w) * 32;

    const int wr = (w >> 1) * 32, wc = (w & 1) * 64;
    const int fr = lane & 15;
    const int kq = lane >> 4;
    int aoff[2][2], boff[2][4], aoffT[2], boffT[4];
    #pragma unroll
    for (int mi = 0; mi < 2; mi++) {
        int ra = wr + mi * 16 + fr;
        aoff[0][mi] = ra * 64 + ((kq)     ^ (ra & 7)) * 8;
        aoff[1][mi] = ra * 64 + ((4 + kq) ^ (ra & 7)) * 8;
        aoffT[mi]   = ra * 32 + (kq ^ ((ra >> 1) & 3)) * 8;
    }
    #pragma unroll
    for (int ni = 0; ni < 4; ni++) {
        int rb = wc + ni * 16 + fr;
        boff[0][ni] = rb * 64 + ((kq)     ^ (rb & 7)) * 8;
        boff[1][ni] = rb * 64 + ((4 + kq) ^ (rb & 7)) * 8;
        boffT[ni]   = rb * 32 + (kq ^ ((rb >> 1) & 3)) * 8;
    }
    f32x4 acc[2][4] = {};

    auto stage64 = [&](int t, int b) {
        const long long go = (long long)t * 64;
        const int bo = b * (128 * 64);
        #pragma unroll
        for (int i = 0; i < 2; i++) {
            gload_lds16(gA[i] + go, &As[0][0] + bo + lo[i]);
            gload_lds16(gB[i] + go, &Bs[0][0] + bo + lo[i]);
        }
    };
    auto stageTail = [&]() {
        gload_lds16(gAT, &As[1][0] + loT);
        gload_lds16(gBT, &Bs[1][0] + loT);
    };
    auto compute64 = [&](int b) {
        const bf* Ab = &As[0][0] + b * (128 * 64);
        const bf* Bb = &Bs[0][0] + b * (128 * 64);
        #pragma unroll
        for (int s = 0; s < 2; s++) {
            bf16x8 af[2], bfr[4];
            #pragma unroll
            for (int mi = 0; mi < 2; mi++) af[mi]  = *(const bf16x8*)(Ab + aoff[s][mi]);
            #pragma unroll
            for (int ni = 0; ni < 4; ni++) bfr[ni] = *(const bf16x8*)(Bb + boff[s][ni]);
            #pragma unroll
            for (int mi = 0; mi < 2; mi++)
                #pragma unroll
                for (int ni = 0; ni < 4; ni++)
                    acc[mi][ni] = __builtin_amdgcn_mfma_f32_16x16x32_bf16(
                        af[mi], bfr[ni], acc[mi][ni], 0, 0, 0);
        }
    };

    stage64(0, 0);
    stage64(1, 1);
    stage64(2, 2);

    #pragma unroll 1
    for (int t = 0; t < 35; t++) {
        asm volatile("s_waitcnt vmcnt(8)" ::: "memory");
        __builtin_amdgcn_s_barrier();
        __builtin_amdgcn_sched_barrier(0);
        compute64(t & 3);
        if (t < 34) stage64(t + 3, (t + 3) & 3);
        else        stageTail();
    }
    asm volatile("s_waitcnt vmcnt(6)" ::: "memory");
    __builtin_amdgcn_s_barrier();
    __builtin_amdgcn_sched_barrier(0);
    compute64(3);
    asm volatile("s_waitcnt vmcnt(2)" ::: "memory");
    __builtin_amdgcn_s_barrier();
    __builtin_amdgcn_sched_barrier(0);
    compute64(0);
    asm volatile("s_waitcnt vmcnt(0)" ::: "memory");
    __builtin_amdgcn_s_barrier();
    __builtin_amdgcn_sched_barrier(0);
    {
        bf16x8 af[2], bfr[4];
        #pragma unroll
        for (int mi = 0; mi < 2; mi++) af[mi]  = *(const bf16x8*)(&As[1][0] + aoffT[mi]);
        #pragma unroll
        for (int ni = 0; ni < 4; ni++) bfr[ni] = *(const bf16x8*)(&Bs[1][0] + boffT[ni]);
        #pragma unroll
        for (int mi = 0; mi < 2; mi++)
            #pragma unroll
            for (int ni = 0; ni < 4; ni++)
                acc[mi][ni] = __builtin_amdgcn_mfma_f32_16x16x32_bf16(
                    af[mi], bfr[ni], acc[mi][ni], 0, 0, 0);
    }

    float* C = part + (long long)z * ((long long)NN * 128);
    const int cr0 = (lane >> 4) * 4;
    const int cc = lane & 15;
    #pragma unroll
    for (int mi = 0; mi < 2; mi++) {
        #pragma unroll
        for (int ni = 0; ni < 4; ni++) {
            int col = wc + ni * 16 + cc;
            #pragma unroll
            for (int j = 0; j < 4; j++) {
                int row = m0 + wr + mi * 16 + cr0 + j;
                C[(long long)row * 128 + col] = acc[mi][ni][j];
            }
        }
    }
}

// ---------------------------------------------------------------------------
// Generic batched MFMA GEMM: C = act(alpha * A @ B^T + bias)
// ---------------------------------------------------------------------------
template<bool A_F32, bool B_F32, bool HAS_BIAS, bool RELU, bool OUT_F32, bool SIDE_A>
__global__ __launch_bounds__(256) void gemm128(
    const void* __restrict__ A, int lda, long long sA1, long long sA2,
    const void* __restrict__ Bm, int ldb, long long sB1, long long sB2,
    const float* __restrict__ bias,
    void* __restrict__ Cv, int ldc, long long sC1, long long sC2,
    int M, int N, int K, int tilesN, int zdiv, float alpha,
    bf* __restrict__ sideA)
{
    __shared__ bf As[128][40];
    __shared__ bf Bs[128][40];
    const int tid = threadIdx.x;
    const int z = blockIdx.y;
    const int zq = z / zdiv, zr = z - zq * zdiv;
    const char* Ap = (const char*)A;
    const char* Bp = (const char*)Bm;
    const long long offA = (long long)zq * sA1 + (long long)zr * sA2;
    const long long offB = (long long)zq * sB1 + (long long)zr * sB2;
    const long long offC = (long long)zq * sC1 + (long long)zr * sC2;
    const int tm = blockIdx.x / tilesN, tn = blockIdx.x - tm * tilesN;
    int m0 = tm * 128; if (m0 > M - 128) m0 = M - 128;
    const int n0 = tn * 128;
    const int lane = tid & 63;
    const int wv = tid >> 6;
    const int wr = (wv >> 1) * 64, wc = (wv & 1) * 64;
    const int fr = lane & 15;
    const int kq = (lane >> 4) * 8;
    const int sr = tid >> 2, scol = (tid & 3) * 8;
    f32x4 acc[4][4] = {};

    for (int k0 = 0; k0 < K; k0 += 32) {
        if (k0 + 32 <= K) {
            const long long ia0 = offA + (long long)(m0 + sr) * lda + k0 + scol;
            const long long ia1 = offA + (long long)(m0 + sr + 64) * lda + k0 + scol;
            short8 va0 = ld8<A_F32>(Ap, ia0);
            short8 va1 = ld8<A_F32>(Ap, ia1);
            short8 vb0 = {0,0,0,0,0,0,0,0}, vb1 = {0,0,0,0,0,0,0,0};
            if (n0 + sr < N)      vb0 = ld8<B_F32>(Bp, offB + (long long)(n0 + sr) * ldb + k0 + scol);
            if (n0 + sr + 64 < N) vb1 = ld8<B_F32>(Bp, offB + (long long)(n0 + sr + 64) * ldb + k0 + scol);
            if (SIDE_A) {
                *(short8*)&sideA[ia0] = va0;
                *(short8*)&sideA[ia1] = va1;
            }
            *(short8*)&As[sr][scol] = va0;
            *(short8*)&As[sr + 64][scol] = va1;
            *(short8*)&Bs[sr][scol] = vb0;
            *(short8*)&Bs[sr + 64][scol] = vb1;
        } else {
            bf zv = f2b(0.f);
            for (int i = tid; i < 128 * 32; i += 256) {
                int r = i >> 5, c = i & 31, gk = k0 + c;
                As[r][c] = (gk < K) ? ldelem<A_F32>(Ap, offA + (long long)(m0 + r) * lda + gk) : zv;
                Bs[r][c] = (gk < K && n0 + r < N) ? ldelem<B_F32>(Bp, offB + (long long)(n0 + r) * ldb + gk) : zv;
            }
        }
        __syncthreads();
        bf16x8 af[4], bfg[4];
        #pragma unroll
        for (int i = 0; i < 4; i++) af[i]  = *(const bf16x8*)&As[wr + i * 16 + fr][kq];
        #pragma unroll
        for (int i = 0; i < 4; i++) bfg[i] = *(const bf16x8*)&Bs[wc + i * 16 + fr][kq];
        #pragma unroll
        for (int mi = 0; mi < 4; mi++)
            #pragma unroll
            for (int ni = 0; ni < 4; ni++)
                acc[mi][ni] = __builtin_amdgcn_mfma_f32_16x16x32_bf16(
                    af[mi], bfg[ni], acc[mi][ni], 0, 0, 0);
        __syncthreads();
    }

    const int cr0 = (lane >> 4) * 4;
    const int cc = lane & 15;
    #pragma unroll
    for (int mi = 0; mi < 4; mi++) {
        #pragma unroll
        for (int ni = 0; ni < 4; ni++) {
            int col = n0 + wc + ni * 16 + cc;
            if (col >= N) continue;
            float bv = 0.f;
            if (HAS_BIAS) bv = bias[col];
            #pragma unroll
            for (int j = 0; j < 4; j++) {
                int row = m0 + wr + mi * 16 + cr0 + j;
                float v = acc[mi][ni][j] * alpha + bv;
                if (RELU) v = fmaxf(v, 0.f);
                if (OUT_F32) ((float*)Cv)[offC + (long long)row * ldc + col] = v;
                else ((bf*)Cv)[offC + (long long)row * ldc + col] = f2b(v);
            }
        }
    }
}

// ---------------------------------------------------------------------------
// S-GEMM with FUSED row softmax: P[z] = softmax_row(alpha * Q_z @ K_z^T).
// BN=512 (full key row per block) -> complete softmax rows in-block.
// grid (4, 80), 512 threads / 8 waves (2M x 4N, 64x128 out/wave), K=32 =
// one MFMA step. Row reduce: 8-ni register fold + shfl_xor over the 16
// cc-lanes + 4-way cross-wave LDS exchange (gemm_ln pattern). Replaces the
// S gemm128 + softmax512 dispatches and their 84 MB Sb round trip.
// ---------------------------------------------------------------------------
__global__ __launch_bounds__(512) void gemm_s(
    const bf* __restrict__ qkv,   // [10240][384]
    bf* __restrict__ Sb)          // [80][512][512]
{
    __shared__ bf Qs[128][40];
    __shared__ bf Ks[512][40];
    __shared__ float red[128][4];
    const int tid = threadIdx.x;
    const int lane = tid & 63;
    const int w = tid >> 6;          // 0..7
    const int z = blockIdx.y;        // n = z>>2, h = z&3
    const int m0 = blockIdx.x * 128;
    const long long offQ = (long long)(z >> 2) * 7680 + (z & 3) * 32;
    const long long offK = offQ + 128;

    // stage Q tile [128][32]: 8 elems/thread
    {
        int r = tid >> 2, c = (tid & 3) * 8;
        *(short8*)&Qs[r][c] = *(const short8*)(qkv + offQ + (long long)(m0 + r) * 7680 + c);
    }
    // stage K [512][32]: 32 elems/thread
    #pragma unroll
    for (int i = 0; i < 4; i++) {
        int r = i * 128 + (tid >> 2), c = (tid & 3) * 8;
        *(short8*)&Ks[r][c] = *(const short8*)(qkv + offK + (long long)r * 7680 + c);
    }
    __syncthreads();

    const int wr = (w >> 2) * 64;    // 0 or 64
    const int wc = (w & 3) * 128;    // 0/128/256/384
    const int wn = w & 3;
    const int fr = lane & 15;
    const int kq = (lane >> 4) * 8;
    bf16x8 af[4], bfg[8];
    #pragma unroll
    for (int mi = 0; mi < 4; mi++) af[mi]  = *(const bf16x8*)&Qs[wr + mi * 16 + fr][kq];
    #pragma unroll
    for (int ni = 0; ni < 8; ni++) bfg[ni] = *(const bf16x8*)&Ks[wc + ni * 16 + fr][kq];
    f32x4 acc[4][8];
    #pragma unroll
    for (int mi = 0; mi < 4; mi++)
        #pragma unroll
        for (int ni = 0; ni < 8; ni++)
            acc[mi][ni] = __builtin_amdgcn_mfma_f32_16x16x32_bf16(
                af[mi], bfg[ni], f32x4{0.f, 0.f, 0.f, 0.f}, 0, 0, 0);

    const float alpha = 0.17677669529663687f;
    const int cr0 = (lane >> 4) * 4;
    const int cc = lane & 15;
    // scale + per-wave row max over this wave's 128 cols
    float mx[4][4];
    #pragma unroll
    for (int mi = 0; mi < 4; mi++)
        #pragma unroll
        for (int j = 0; j < 4; j++) {
            float m = -3.0e38f;
            #pragma unroll
            for (int ni = 0; ni < 8; ni++) {
                acc[mi][ni][j] *= alpha;
                m = fmaxf(m, acc[mi][ni][j]);
            }
            #pragma unroll
            for (int off = 1; off < 16; off <<= 1)
                m = fmaxf(m, __shfl_xor(m, off, 64));
            mx[mi][j] = m;
        }
    if (cc == 0) {
        #pragma unroll
        for (int mi = 0; mi < 4; mi++)
            #pragma unroll
            for (int j = 0; j < 4; j++)
                red[wr + mi * 16 + cr0 + j][wn] = mx[mi][j];
    }
    __syncthreads();
    #pragma unroll
    for (int mi = 0; mi < 4; mi++)
        #pragma unroll
        for (int j = 0; j < 4; j++) {
            int lr = wr + mi * 16 + cr0 + j;
            mx[mi][j] = fmaxf(fmaxf(red[lr][0], red[lr][1]),
                              fmaxf(red[lr][2], red[lr][3]));
        }
    __syncthreads();   // all reads of red done before rewrite
    // exp + per-wave row sum
    float sm[4][4];
    #pragma unroll
    for (int mi = 0; mi < 4; mi++)
        #pragma unroll
        for (int j = 0; j < 4; j++) {
            float s = 0.f;
            #pragma unroll
            for (int ni = 0; ni < 8; ni++) {
                float p = __expf(acc[mi][ni][j] - mx[mi][j]);
                acc[mi][ni][j] = p;
                s += p;
            }
            #pragma unroll
            for (int off = 1; off < 16; off <<= 1)
                s += __shfl_xor(s, off, 64);
            sm[mi][j] = s;
        }
    if (cc == 0) {
        #pragma unroll
        for (int mi = 0; mi < 4; mi++)
            #pragma unroll
            for (int j = 0; j < 4; j++)
                red[wr + mi * 16 + cr0 + j][wn] = sm[mi][j];
    }
    __syncthreads();
    bf* out = Sb + (long long)z * 262144;
    #pragma unroll
    for (int mi = 0; mi < 4; mi++)
        #pragma unroll
        for (int j = 0; j < 4; j++) {
            int lr = wr + mi * 16 + cr0 + j;
            float inv = 1.f / (red[lr][0] + red[lr][1] + red[lr][2] + red[lr][3]);
            #pragma unroll
            for (int ni = 0; ni < 8; ni++)
                out[(long long)(m0 + lr) * 512 + wc + ni * 16 + cc] =
                    f2b(acc[mi][ni][j] * inv);
        }
}

// ---------------------------------------------------------------------------
// h-GEMM with FUSED 5-way partial reduce on the A operand (R20-verified).
// ---------------------------------------------------------------------------
__global__ __launch_bounds__(512) void gemm_h(
    const float* __restrict__ part,   // [AZ][NN][128]
    const bf* __restrict__ Bw,        // w1T [256][128]
    const float* __restrict__ bias,   // b1 [256]
    bf* __restrict__ H)               // [NN][256]
{
    __shared__ bf As[128][40];
    __shared__ bf Bs[256][40];
    const int tid = threadIdx.x;
    int m0 = blockIdx.x * 128;
    if (m0 > NN - 128) m0 = NN - 128;
    const int lane = tid & 63;
    const int w = tid >> 6;
    const int wr = (w >> 2) * 64, wc = (w & 3) * 64;
    const int fr = lane & 15;
    const int kq = (lane >> 4) * 8;
    const long long zs = (long long)NN * 128;
    const int sr = tid >> 2, scol = (tid & 3) * 8;
    const int sr2 = tid >> 1, scol2 = (tid & 1) * 16;
    f32x4 acc[4][4] = {};

    for (int k0 = 0; k0 < 128; k0 += 32) {
        {
            const float* pb = part + (long long)(m0 + sr) * 128 + k0 + scol;
            f32x4 s0 = *(const f32x4*)(pb);
            f32x4 s1 = *(const f32x4*)(pb + 4);
            #pragma unroll
            for (int z = 1; z < AZ; z++) {
                s0 += *(const f32x4*)(pb + (long long)z * zs);
                s1 += *(const f32x4*)(pb + (long long)z * zs + 4);
            }
            short8 v;
            #pragma unroll
            for (int j = 0; j < 4; j++) {
                v[j]     = (short)f2us(s0[j]);
                v[4 + j] = (short)f2us(s1[j]);
            }
            *(short8*)&As[sr][scol] = v;
        }
        *(short8*)&Bs[sr2][scol2]     = *(const short8*)(Bw + (long long)sr2 * 128 + k0 + scol2);
        *(short8*)&Bs[sr2][scol2 + 8] = *(const short8*)(Bw + (long long)sr2 * 128 + k0 + scol2 + 8);
        __syncthreads();
        bf16x8 af[4], bfg[4];
        #pragma unroll
        for (int i = 0; i < 4; i++) af[i]  = *(const bf16x8*)&As[wr + i * 16 + fr][kq];
        #pragma unroll
        for (int i = 0; i < 4; i++) bfg[i] = *(const bf16x8*)&Bs[wc + i * 16 + fr][kq];
        #pragma unroll
        for (int mi = 0; mi < 4; mi++)
            #pragma unroll
            for (int ni = 0; ni < 4; ni++)
                acc[mi][ni] = __builtin_amdgcn_mfma_f32_16x16x32_bf16(
                    af[mi], bfg[ni], acc[mi][ni], 0, 0, 0);
        __syncthreads();
    }

    const int cr0 = (lane >> 4) * 4;
    const int cc = lane & 15;
    #pragma unroll
    for (int mi = 0; mi < 4; mi++) {
        #pragma unroll
        for (int ni = 0; ni < 4; ni++) {
            int col = wc + ni * 16 + cc;
            float bv = bias[col];
            #pragma unroll
            for (int j = 0; j < 4; j++) {
                int row = m0 + wr + mi * 16 + cr0 + j;
                H[(long long)row * 256 + col] = f2b(fmaxf(acc[mi][ni][j] + bv, 0.f));
            }
        }
    }
}

// ---------------------------------------------------------------------------
// nf GEMM with fused BT write (R19-verified).
// ---------------------------------------------------------------------------
__global__ __launch_bounds__(256) void gemm_nf(
    const float* __restrict__ A,     // node_feature [NN][400]
    const float* __restrict__ Bw,    // f1w [128][400]
    const float* __restrict__ bias,  // f1b [128]
    const float* __restrict__ emb,   // [NN][128] f32
    bf* __restrict__ nfp,            // [NN][128]
    bf* __restrict__ BT)             // [128][NN]
{
    __shared__ bf As[128][40];
    __shared__ bf Bs[128][40];
    const int tid = threadIdx.x;
    int m0 = blockIdx.x * 128;
    if (m0 > NN - 128) m0 = NN - 128;
    const int lane = tid & 63;
    const int wv = tid >> 6;
    const int wr = (wv >> 1) * 64, wc = (wv & 1) * 64;
    const int fr = lane & 15;
    const int kq = (lane >> 4) * 8;
    const int sr = tid >> 2, scol = (tid & 3) * 8;
    f32x4 acc[4][4] = {};

    for (int k0 = 0; k0 < FFEAT; k0 += 32) {
        if (k0 + 32 <= FFEAT) {
            *(short8*)&As[sr][scol]      = ld8<true>(A, (long long)(m0 + sr) * FFEAT + k0 + scol);
            *(short8*)&As[sr + 64][scol] = ld8<true>(A, (long long)(m0 + sr + 64) * FFEAT + k0 + scol);
            *(short8*)&Bs[sr][scol]      = ld8<true>(Bw, (long long)sr * FFEAT + k0 + scol);
            *(short8*)&Bs[sr + 64][scol] = ld8<true>(Bw, (long long)(sr + 64) * FFEAT + k0 + scol);
        } else {
            bf zv = f2b(0.f);
            for (int i = tid; i < 128 * 32; i += 256) {
                int r = i >> 5, c = i & 31, gk = k0 + c;
                As[r][c] = (gk < FFEAT) ? f2b(A[(long long)(m0 + r) * FFEAT + gk]) : zv;
                Bs[r][c] = (gk < FFEAT) ? f2b(Bw[(long long)r * FFEAT + gk]) : zv;
            }
        }
        __syncthreads();
        bf16x8 af[4], bfg[4];
        #pragma unroll
        for (int i = 0; i < 4; i++) af[i]  = *(const bf16x8*)&As[wr + i * 16 + fr][kq];
        #pragma unroll
        for (int i = 0; i < 4; i++) bfg[i] = *(const bf16x8*)&Bs[wc + i * 16 + fr][kq];
        #pragma unroll
        for (int mi = 0; mi < 4; mi++)
            #pragma unroll
            for (int ni = 0; ni < 4; ni++)
                acc[mi][ni] = __builtin_amdgcn_mfma_f32_16x16x32_bf16(
                    af[mi], bfg[ni], acc[mi][ni], 0, 0, 0);
        __syncthreads();
    }

    const int cr0 = (lane >> 4) * 4;
    const int cc = lane & 15;
    #pragma unroll
    for (int mi = 0; mi < 4; mi++) {
        #pragma unroll
        for (int ni = 0; ni < 4; ni++) {
            int col = wc + ni * 16 + cc;
            int rowb = m0 + wr + mi * 16 + cr0;
            float bv = bias[col];
            short4v tv;
            #pragma unroll
            for (int j = 0; j < 4; j++) {
                bf nv = f2b(acc[mi][ni][j] + bv);
                nfp[(long long)(rowb + j) * 128 + col] = nv;
                tv[j] = (short)f2us(b2f(nv) * emb[(long long)(rowb + j) * 128 + col]);
            }
            *(short4v*)&BT[(long long)col * NN + rowb] = tv;
        }
    }
}

// ---------------------------------------------------------------------------
// t2 GEMM with TRANSPOSED output (R16-verified).
// ---------------------------------------------------------------------------
__global__ __launch_bounds__(256) void gemm_t2(
    const bf* __restrict__ A,
    const bf* __restrict__ Bw,
    bf* __restrict__ BT)
{
    __shared__ bf As[128][40];
    __shared__ bf Bs[128][40];
    const int tid = threadIdx.x;
    int m0 = blockIdx.x * 128;
    if (m0 > NN - 128) m0 = NN - 128;
    const int lane = tid & 63;
    const int wv = tid >> 6;
    const int wr = (wv >> 1) * 64, wc = (wv & 1) * 64;
    const int fr = lane & 15;
    const int kq = (lane >> 4) * 8;
    const int sr = tid >> 2, scol = (tid & 3) * 8;
    f32x4 acc[4][4] = {};

    for (int k0 = 0; k0 < 256; k0 += 32) {
        *(short8*)&As[sr][scol]      = ld8<false>(A, (long long)(m0 + sr) * 256 + k0 + scol);
        *(short8*)&As[sr + 64][scol] = ld8<false>(A, (long long)(m0 + sr + 64) * 256 + k0 + scol);
        *(short8*)&Bs[sr][scol]      = ld8<false>(Bw, (long long)sr * 256 + k0 + scol);
        *(short8*)&Bs[sr + 64][scol] = ld8<false>(Bw, (long long)(sr + 64) * 256 + k0 + scol);
        __syncthreads();
        bf16x8 af[4], bfg[4];
        #pragma unroll
        for (int i = 0; i < 4; i++) af[i]  = *(const bf16x8*)&As[wr + i * 16 + fr][kq];
        #pragma unroll
        for (int i = 0; i < 4; i++) bfg[i] = *(const bf16x8*)&Bs[wc + i * 16 + fr][kq];
        #pragma unroll
        for (int mi = 0; mi < 4; mi++)
            #pragma unroll
            for (int ni = 0; ni < 4; ni++)
                acc[mi][ni] = __builtin_amdgcn_mfma_f32_16x16x32_bf16(
                    af[mi], bfg[ni], acc[mi][ni], 0, 0, 0);
        __syncthreads();
    }

    const int cr0 = (lane >> 4) * 4;
    const int cc = lane & 15;
    #pragma unroll
    for (int mi = 0; mi < 4; mi++) {
        #pragma unroll
        for (int ni = 0; ni < 4; ni++) {
            int col = wc + ni * 16 + cc;
            int rowb = m0 + wr + mi * 16 + cr0;
            short4v v;
            #pragma unroll
            for (int j = 0; j < 4; j++) v[j] = (short)f2us(acc[mi][ni][j]);
            *(short4v*)&BT[(long long)col * NN + rowb] = v;
        }
    }
}

// ---------------------------------------------------------------------------
// 5-way partial reduce + bias with transposed output (R16-verified).
// ---------------------------------------------------------------------------
__global__ __launch_bounds__(256) void reduceKT(
    const float* __restrict__ part, const float* __restrict__ bias,
    bf* __restrict__ BT)
{
    __shared__ bf t[32][33];
    const long long zs = (long long)NN * 128;
    int r0 = blockIdx.x * 32, c0 = blockIdx.y * 32;
    int tx = threadIdx.x, ty = threadIdx.y;   // 32 x 8
    #pragma unroll
    for (int i = 0; i < 4; i++) {
        int r = r0 + ty + i * 8, c = c0 + tx;
        float s = bias[c];
        #pragma unroll
        for (int z = 0; z < AZ; z++) s += part[(long long)z * zs + (long long)r * 128 + c];
        t[ty + i * 8][tx] = f2b(s);
    }
    __syncthreads();
    #pragma unroll
    for (int i = 0; i < 4; i++) {
        int c = c0 + ty + i * 8, r = r0 + tx;
        BT[(long long)c * NN + r] = t[tx][ty + i * 8];
    }
}

// ---------------------------------------------------------------------------
// GEMM with fused residual + LayerNorm epilogue (R15-verified).
// ---------------------------------------------------------------------------
__global__ __launch_bounds__(256) void gemm_ln(
    const bf* __restrict__ A, int lda,
    const float* __restrict__ Bw,
    const float* __restrict__ bias,
    const bf* __restrict__ resid,
    const float* __restrict__ lnS, const float* __restrict__ lnB,
    bf* __restrict__ outp, int K)
{
    __shared__ bf As[128][40];
    __shared__ bf Bs[128][40];
    __shared__ float red[128][2][2];
    const int tid = threadIdx.x;
    const int m0 = blockIdx.x * 128;
    const int lane = tid & 63;
    const int wv = tid >> 6;
    const int wr = (wv >> 1) * 64, wc = (wv & 1) * 64;
    const int fr = lane & 15;
    const int kq = (lane >> 4) * 8;
    const int sr = tid >> 2, scol = (tid & 3) * 8;
    f32x4 acc[4][4] = {};

    for (int k0 = 0; k0 < K; k0 += 32) {
        short8 va0 = ld8<false>(A, (long long)(m0 + sr) * lda + k0 + scol);
        short8 va1 = ld8<false>(A, (long long)(m0 + sr + 64) * lda + k0 + scol);
        short8 vb0 = ld8<true>(Bw, (long long)sr * K + k0 + scol);
        short8 vb1 = ld8<true>(Bw, (long long)(sr + 64) * K + k0 + scol);
        *(short8*)&As[sr][scol] = va0;
        *(short8*)&As[sr + 64][scol] = va1;
        *(short8*)&Bs[sr][scol] = vb0;
        *(short8*)&Bs[sr + 64][scol] = vb1;
        __syncthreads();
        bf16x8 af[4], bfg[4];
        #pragma unroll
        for (int i = 0; i < 4; i++) af[i]  = *(const bf16x8*)&As[wr + i * 16 + fr][kq];
        #pragma unroll
        for (int i = 0; i < 4; i++) bfg[i] = *(const bf16x8*)&Bs[wc + i * 16 + fr][kq];
        #pragma unroll
        for (int mi = 0; mi < 4; mi++)
            #pragma unroll
            for (int ni = 0; ni < 4; ni++)
                acc[mi][ni] = __builtin_amdgcn_mfma_f32_16x16x32_bf16(
                    af[mi], bfg[ni], acc[mi][ni], 0, 0, 0);
        __syncthreads();
    }

    const int cr0 = (lane >> 4) * 4;
    const int cc = lane & 15;
    #pragma unroll
    for (int mi = 0; mi < 4; mi++)
        #pragma unroll
        for (int ni = 0; ni < 4; ni++) {
            int col = wc + ni * 16 + cc;
            #pragma unroll
            for (int j = 0; j < 4; j++) {
                int row = m0 + wr + mi * 16 + cr0 + j;
                acc[mi][ni][j] += bias[col] + b2f(resid[(long long)row * 128 + col]);
            }
        }
    float s1[4][4], s2[4][4];
    #pragma unroll
    for (int mi = 0; mi < 4; mi++)
        #pragma unroll
        for (int j = 0; j < 4; j++) {
            float a = 0.f, b = 0.f;
            #pragma unroll
            for (int ni = 0; ni < 4; ni++) {
                float x = acc[mi][ni][j];
                a += x; b += x * x;
            }
            #pragma unroll
            for (int off = 1; off < 16; off <<= 1) {
                a += __shfl_xor(a, off, 64);
                b += __shfl_xor(b, off, 64);
            }
            s1[mi][j] = a; s2[mi][j] = b;
        }
    if (cc == 0) {
        #pragma unroll
        for (int mi = 0; mi < 4; mi++)
            #pragma unroll
            for (int j = 0; j < 4; j++) {
                int lr = wr + mi * 16 + cr0 + j;
                red[lr][wv & 1][0] = s1[mi][j];
                red[lr][wv & 1][1] = s2[mi][j];
            }
    }
    __syncthreads();
    #pragma unroll
    for (int mi = 0; mi < 4; mi++)
        #pragma unroll
        for (int ni = 0; ni < 4; ni++) {
            int col = wc + ni * 16 + cc;
            float ls = lnS[col], lb = lnB[col];
            #pragma unroll
            for (int j = 0; j < 4; j++) {
                int lr = wr + mi * 16 + cr0 + j;
                float tot  = red[lr][0][0] + red[lr][1][0];
                float tot2 = red[lr][0][1] + red[lr][1][1];
                float mean = tot * (1.f / 128.f);
                float var  = tot2 * (1.f / 128.f) - mean * mean;
                float inv  = rsqrtf(var + 1e-5f);
                outp[(long long)(m0 + lr) * 128 + col] =
                    f2b((acc[mi][ni][j] - mean) * inv * ls + lb);
            }
        }
}

// ---------------------------------------------------------------------------
// scores GEMM with split B source (R15-verified).
// ---------------------------------------------------------------------------
__global__ __launch_bounds__(256) void gemm_scores(
    const bf* __restrict__ A,    // cp [512][256]
    const bf* __restrict__ B1,   // item [NN][128]
    const bf* __restrict__ B2,   // nf   [NN][128]
    float* __restrict__ outp)    // [512][NN]
{
    __shared__ bf As[128][40];
    __shared__ bf Bs[128][40];
    const int tid = threadIdx.x;
    const int tm = blockIdx.x / 94, tn = blockIdx.x - tm * 94;
    const int m0 = tm * 128;
    const int n0 = tn * 128;
    const int lane = tid & 63;
    const int wv = tid >> 6;
    const int wr = (wv >> 1) * 64, wc = (wv & 1) * 64;
    const int fr = lane & 15;
    const int kq = (lane >> 4) * 8;
    const int sr = tid >> 2, scol = (tid & 3) * 8;
    f32x4 acc[4][4] = {};

    for (int k0 = 0; k0 < 256; k0 += 32) {
        short8 va0 = ld8<false>(A, (long long)(m0 + sr) * 256 + k0 + scol);
        short8 va1 = ld8<false>(A, (long long)(m0 + sr + 64) * 256 + k0 + scol);
        const int gk = k0 + scol;
        const bf* bb = (gk < 128) ? B1 : B2;
        const int kk = gk & 127;
        short8 vb0 = {0,0,0,0,0,0,0,0}, vb1 = {0,0,0,0,0,0,0,0};
        if (n0 + sr < NN)      vb0 = *(const short8*)(bb + (long long)(n0 + sr) * 128 + kk);
        if (n0 + sr + 64 < NN) vb1 = *(const short8*)(bb + (long long)(n0 + sr + 64) * 128 + kk);
        *(short8*)&As[sr][scol] = va0;
        *(short8*)&As[sr + 64][scol] = va1;
        *(short8*)&Bs[sr][scol] = vb0;
        *(short8*)&Bs[sr + 64][scol] = vb1;
        __syncthreads();
        bf16x8 af[4], bfg[4];
        #pragma unroll
        for (int i = 0; i < 4; i++) af[i]  = *(const bf16x8*)&As[wr + i * 16 + fr][kq];
        #pragma unroll
        for (int i = 0; i < 4; i++) bfg[i] = *(const bf16x8*)&Bs[wc + i * 16 + fr][kq];
        #pragma unroll
        for (int mi = 0; mi < 4; mi++)
            #pragma unroll
            for (int ni = 0; ni < 4; ni++)
                acc[mi][ni] = __builtin_amdgcn_mfma_f32_16x16x32_bf16(
                    af[mi], bfg[ni], acc[mi][ni], 0, 0, 0);
        __syncthreads();
    }

    const int cr0 = (lane >> 4) * 4;
    const int cc = lane & 15;
    #pragma unroll
    for (int mi = 0; mi < 4; mi++) {
        #pragma unroll
        for (int ni = 0; ni < 4; ni++) {
            int col = n0 + wc + ni * 16 + cc;
            if (col >= NN) continue;
            #pragma unroll
            for (int j = 0; j < 4; j++) {
                int row = m0 + wr + mi * 16 + cr0 + j;
                outp[(long long)row * NN + col] = acc[mi][ni][j];
            }
        }
    }
}

// all 4 GCN weight transposes in one dispatch
__global__ __launch_bounds__(256) void transpose4_k(
    const float* s0, const float* s1, const float* s2, const float* s3,
    bf* d0, bf* d1, bf* d2, bf* d3)
{
    __shared__ bf t[32][33];
    const int z = blockIdx.z;
    const float* in = (z == 0) ? s0 : (z == 1) ? s1 : (z == 2) ? s2 : s3;
    bf* out = (z == 0) ? d0 : (z == 1) ? d1 : (z == 2) ? d2 : d3;
    const int R = (z & 1) ? HIDC : DD;
    const int C = (z & 1) ? DD : HIDC;
    int r0 = blockIdx.x * 32, c0 = blockIdx.y * 32;
    if (r0 >= R || c0 >= C) return;
    int tx = threadIdx.x, ty = threadIdx.y;   // 32 x 8
    #pragma unroll
    for (int i = 0; i < 4; i++) {
        int r = r0 + ty + i * 8, c = c0 + tx;
        bf v = f2b(0.f);
        if (r < R && c < C) v = f2b(in[(long long)r * C + c]);
        t[ty + i * 8][tx] = v;
    }
    __syncthreads();
    #pragma unroll
    for (int i = 0; i < 4; i++) {
        int c = c0 + ty + i * 8, r = r0 + tx;
        if (c < C && r < R) out[(long long)c * R + r] = t[tx][ty + i * 8];
    }
}

template<bool IN_F32>
__global__ __launch_bounds__(256) void transpose_k(
    const void* __restrict__ in, int ldin, long long sI1, long long sI2, int zdiv,
    const float* __restrict__ mulp, int ldmul,
    bf* __restrict__ outp, int ldout, long long sOut,
    int R, int C)
{
    __shared__ bf t[32][33];
    const int z = blockIdx.z;
    const int zq = z / zdiv, zr = z - zq * zdiv;
    const long long offI = (long long)zq * sI1 + (long long)zr * sI2;
    bf* op = outp + (long long)z * sOut;
    int r0 = blockIdx.x * 32, c0 = blockIdx.y * 32;
    int tx = threadIdx.x, ty = threadIdx.y;   // 32 x 8
    #pragma unroll
    for (int i = 0; i < 4; i++) {
        int r = r0 + ty + i * 8, c = c0 + tx;
        bf v = f2b(0.f);
        if (r < R && c < C) {
            v = ldelem<IN_F32>(in, offI + (long long)r * ldin + c);
            if (mulp) v = f2b(b2f(v) * mulp[(long long)r * ldmul + c]);
        }
        t[ty + i * 8][tx] = v;
    }
    __syncthreads();
    #pragma unroll
    for (int i = 0; i < 4; i++) {
        int c = c0 + ty + i * 8, r = r0 + tx;
        if (c < C && r < R) op[(long long)c * ldout + r] = t[tx][ty + i * 8];
    }
}

__global__ __launch_bounds__(256) void reduceK(
    const float* __restrict__ part, const float* __restrict__ bias,
    bf* __restrict__ outp, int total, int nz, long long zs)
{
    int i = blockIdx.x * 256 + threadIdx.x;
    if (i >= total) return;
    float s = 0.f;
    for (int zz = 0; zz < nz; zz++) s += part[(long long)zz * zs + i];
    if (bias) s += bias[i & 127];
    outp[i] = f2b(s);
}

__global__ __launch_bounds__(256) void gather_rows(
    const bf* __restrict__ src, const int* __restrict__ idx,
    bf* __restrict__ dst, int nrows)
{
    int t = blockIdx.x * 256 + threadIdx.x;
    int row = t >> 4, p = t & 15;
    if (row >= nrows) return;
    long long srow = idx[row];
    *(short8*)&dst[(long long)row * 128 + p * 8] =
        *(const short8*)&src[srow * 128 + p * 8];
}

__global__ __launch_bounds__(256) void build_citing(
    const bf* __restrict__ x2, const bf* __restrict__ nf,
    const int* __restrict__ citing, bf* __restrict__ cp)
{
    int i = blockIdx.x * 256 + threadIdx.x;
    if (i >= BBATCH * 256) return;
    int b = i >> 8, d = i & 255;
    float v;
    if (d < 128) {
        float s = 0.f;
        for (int l = 0; l < LSEQ; l++)
            s += b2f(x2[((long long)b * LSEQ + l) * 128 + d]);
        v = s * (1.f / (float)LSEQ);
    } else {
        v = b2f(nf[(long long)citing[b] * 128 + (d - 128)]);
    }
    cp[i] = f2b(v);
}

// ---------------------------------------------------------------------------
extern "C" void kernel_launch(void* const* d_in, const int* in_sizes, int n_in,
                              void* d_out, int out_size, void* d_ws, size_t ws_size,
                              hipStream_t stream)
{
    const float* emb  = (const float*)d_in[0];
    const float* f1w  = (const float*)d_in[1];
    const float* f1b  = (const float*)d_in[2];
    const float* g0w1 = (const float*)d_in[3];  const float* g0b1 = (const float*)d_in[4];
    const float* g0w2 = (const float*)d_in[5];  const float* g0b2 = (const float*)d_in[6];
    const float* g1w1 = (const float*)d_in[7];  const float* g1b1 = (const float*)d_in[8];
    const float* g1w2 = (const float*)d_in[9];  const float* g1b2 = (const float*)d_in[10];
    const float* ipw  = (const float*)d_in[11]; const float* ipb  = (const float*)d_in[12];
    const float* opw  = (const float*)d_in[13]; const float* opb  = (const float*)d_in[14];
    const float* ln1s = (const float*)d_in[15]; const float* ln1b = (const float*)d_in[16];
    const float* ff1w = (const float*)d_in[17]; const float* ff1b = (const float*)d_in[18];
    const float* ff2w = (const float*)d_in[19]; const float* ff2b = (const float*)d_in[20];
    const float* ln2s = (const float*)d_in[21]; const float* ln2b = (const float*)d_in[22];
    const float* adj  = (const float*)d_in[23];
    const float* nfe  = (const float*)d_in[24];
    const int* citing = (const int*)d_in[26];
    const int* useqs  = (const int*)d_in[28];
    float* outp = (float*)d_out;

    size_t off = 0;
    auto carve = [&](size_t bytes) -> char* {
        char* p = (char*)d_ws + off;
        off += (bytes + 255) & ~(size_t)255;
        return p;
    };
    bf* adjb = (bf*)carve((size_t)NN * NN * 2);       // bf16 copy of adj (288 MB)
    bf* nf   = (bf*)carve((size_t)NN * DD * 2);
    bf* bufP = (bf*)carve((size_t)NN * DD * 2);
    bf* bufQ = (bf*)carve((size_t)NN * DD * 2);
    bf* BT   = (bf*)carve((size_t)NN * DD * 2);       // transposed [128][12000]
    bf* Hbuf = (bf*)carve((size_t)NN * HIDC * 2);
    float* part = (float*)carve((size_t)AZ * NN * DD * 4);   // 30 MB
    bf* seq  = (bf*)carve((size_t)10240 * DD * 2);
    bf* qkv  = (bf*)carve((size_t)10240 * 384 * 2);
    bf* Sb   = (bf*)carve((size_t)80 * 512 * 512 * 2);
    bf* w10T = (bf*)carve((size_t)DD * HIDC * 2);
    bf* w20T = (bf*)carve((size_t)DD * HIDC * 2);
    bf* w11T = (bf*)carve((size_t)DD * HIDC * 2);
    bf* w21T = (bf*)carve((size_t)DD * HIDC * 2);
    // aliases (regions dead by the time these are live)
    bf* x1ln = (bf*)Hbuf;
    bf* cp   = (bf*)((char*)Hbuf + (size_t)10240 * DD * 2);
    char* pr = (char*)part;
    bf* VT   = (bf*)pr; pr += (size_t)80 * 32 * 512 * 2;
    bf* o_   = (bf*)pr; pr += (size_t)10240 * DD * 2;
    bf* ffh  = (bf*)pr; pr += (size_t)10240 * FFDIM * 2;
    bf* x2   = (bf*)pr; pr += (size_t)10240 * DD * 2;

    dim3 tb(256), tb512(512), tt(32, 8);
    const long long NM = (long long)NN * DD;   // 1,536,000

    // all 4 GCN weight transposes in one dispatch
    transpose4_k<<<dim3(8, 8, 4), tt, 0, stream>>>(
        g0w1, g0w2, g1w1, g1w2, w10T, w20T, w11T, w21T);

    // nf = node_feature @ f1_w^T + f1_b  AND  BT = (emb .* nf)^T  (fused)
    gemm_nf<<<dim3(94), tb, 0, stream>>>(nfe, f1w, f1b, emb, nf, BT);

    const float* biases1[2] = { g0b1, g1b1 };
    const bf* w1T[2] = { w10T, w11T };
    const bf* w2T[2] = { w20T, w21T };

    for (int g = 0; g < 2; g++) {
        // t = A @ x  (x^T in BT), K-split 5
        if (g == 0) {
            gemm128<true, false, false, false, true, true><<<dim3(94, AZ), tb, 0, stream>>>(
                adj, NN, AKS, 0, BT, NN, AKS, 0, nullptr,
                part, DD, NM, 0, NN, DD, AKS, 1, 1, 1.f, adjb);
        } else {
            adj_gemm8<<<dim3(94, AZ), tb512, 0, stream>>>(adjb, BT, part);
        }
        // h = relu((sum_z part) @ W1 + b1)  (fused reduce + GEMM, BN=256)
        gemm_h<<<dim3(94), tb512, 0, stream>>>(part, w1T[g], biases1[g], Hbuf);
        // BT = (h @ W2)^T  directly
        gemm_t2<<<dim3(94), tb, 0, stream>>>(Hbuf, w2T[g], BT);
        // x' = A @ t2 + b2
        adj_gemm8<<<dim3(94, AZ), tb512, 0, stream>>>(adjb, BT, part);
        if (g == 0) {
            reduceKT<<<dim3(375, 4), tt, 0, stream>>>(part, g0b2, BT);
        } else {
            reduceK<<<dim3((NM + 255) / 256), tb, 0, stream>>>(part, g1b2, bufQ, (int)NM, AZ, NM);
        }
    }
    bf* item = bufQ;

    // seq = item[u_seqs]   [10240,128]
    gather_rows<<<dim3(640), tb, 0, stream>>>(item, useqs, seq, 10240);
    // qkv = seq @ in_proj_w^T + b   [10240,384]
    gemm128<false, true, true, false, false, false><<<dim3(240, 1), tb, 0, stream>>>(
        seq, DD, 0, 0, ipw, DD, 0, 0, ipb,
        qkv, 384, 0, 0, 10240, 384, DD, 3, 1, 1.f, nullptr);
    // VT[z=(n,h)][d][t] from qkv V slice
    transpose_k<false><<<dim3(16, 1, 80), tt, 0, stream>>>(
        qkv + 256, 7680, 384, 32, 4, nullptr, 0, VT, 512, 16384, 512, 32);
    // P = softmax(alpha * Q @ K^T)  (fused S-GEMM + row softmax)
    gemm_s<<<dim3(4, 80), tb512, 0, stream>>>(qkv, Sb);
    // o = P @ V   -> o[s][n][h*32+d]
    gemm128<false, false, false, false, false, false><<<dim3(4, 80), tb, 0, stream>>>(
        Sb, 512, (long long)4 * 262144, 262144, VT, 512, (long long)4 * 16384, 16384, nullptr,
        o_, 2560, 128, 32, 512, 32, 512, 1, 4, 1.f, nullptr);
    // x1 = LN(seq + o @ out_proj^T + b)   (fused GEMM+residual+LN)
    gemm_ln<<<dim3(80), tb, 0, stream>>>(o_, DD, opw, opb, seq, ln1s, ln1b, x1ln, DD);
    // ffh = relu(x1 @ ff1^T + b)   [10240,512]
    gemm128<false, true, true, true, false, false><<<dim3(320, 1), tb, 0, stream>>>(
        x1ln, DD, 0, 0, ff1w, DD, 0, 0, ff1b,
        ffh, FFDIM, 0, 0, 10240, FFDIM, DD, 4, 1, 1.f, nullptr);
    // x2 = LN(x1 + ffh @ ff2^T + b)   (fused GEMM+residual+LN)
    gemm_ln<<<dim3(80), tb, 0, stream>>>(ffh, FFDIM, ff2w, ff2b, x1ln, ln2s, ln2b, x2, FFDIM);
    // citing_paper
    build_citing<<<dim3(512), tb, 0, stream>>>(x2, nf, citing, cp);
    // scores = cp @ [item|nf]^T   [512,12000]  (f32 out, split-B)
    gemm_scores<<<dim3(376), tb, 0, stream>>>(cp, item, nf, outp);
}